// Round 2
// baseline (1523.481 us; speedup 1.0000x reference)
//
#include <hip/hip_runtime.h>
#include <hip/hip_bf16.h>
#include <math.h>

#define CC 256
#define CQn 32
#define HH 64
#define WW 64
#define NN 4096
#define EPSF 1e-5f

typedef __hip_bfloat16 bf16;

typedef __attribute__((ext_vector_type(8))) short bf16x8v;
typedef __attribute__((ext_vector_type(4))) float f32x4v;

__device__ __forceinline__ float b2f(bf16 v) { return __bfloat162float(v); }
__device__ __forceinline__ bf16 f2b(float v) { return __float2bfloat16(v); }

template<typename T> __device__ __forceinline__ float ldf(const T* p, size_t i);
template<> __device__ __forceinline__ float ldf<float>(const float* p, size_t i) { return p[i]; }
template<> __device__ __forceinline__ float ldf<bf16>(const bf16* p, size_t i)  { return b2f(p[i]); }

__device__ __forceinline__ void stf(float* p, size_t i, float v) { p[i] = v; }
__device__ __forceinline__ void stf(bf16* p, size_t i, float v)  { p[i] = f2b(v); }

// ---------------- K0: dtype detector ----------------
__global__ __launch_bounds__(256)
void detect_kernel(const unsigned short* __restrict__ x1, int* __restrict__ flag)
{
    __shared__ int bad;
    if (threadIdx.x == 0) bad = 0;
    __syncthreads();
    int mybad = 0;
    for (int i = threadIdx.x; i < 16384; i += 256) {
        unsigned short u = x1[i];
        if ((u & 0x7F80u) == 0x7F80u) mybad = 1;
    }
    if (mybad) atomicOr(&bad, 1);
    __syncthreads();
    if (threadIdx.x == 0) *flag = bad ? 1 : 0;
}

// ---------------- bf16 path prep 1: x [256][4096] -> xT [4096][256] ----------------
__global__ __launch_bounds__(256)
void transpose_kernel(const int* __restrict__ dflag,
                      const bf16* __restrict__ x, bf16* __restrict__ xT)
{
    if (*dflag != 0) return;
    const int ci0 = blockIdx.x * 64;   // gridDim.x = 4
    const int p0  = blockIdx.y * 64;   // gridDim.y = 64
    const int t = threadIdx.x;
    const int r0 = t >> 3;             // 0..31
    const int ch = t & 7;              // 8 chunks of 8 bf16

    __shared__ bf16 tile[64][72];

    #pragma unroll
    for (int pass = 0; pass < 2; ++pass) {
        int r = pass * 32 + r0;
        uint4 v = *(const uint4*)(x + (size_t)(ci0 + r) * NN + p0 + ch * 8);
        *(uint4*)&tile[r][ch * 8] = v;
    }
    __syncthreads();
    #pragma unroll
    for (int pass = 0; pass < 2; ++pass) {
        int p = pass * 32 + r0;
        bf16 tmp[8];
        #pragma unroll
        for (int j = 0; j < 8; ++j) tmp[j] = tile[ch * 8 + j][p];
        *(uint4*)(xT + (size_t)(p0 + p) * CC + ci0 + ch * 8) = *(const uint4*)tmp;
    }
}

// ---------------- bf16 path prep 2: weights -> Wr[kk][m][ci], m = 2*o + isY ----------------
// w layout: (O=256, I=256, 3, 3). Wr: [9][512][256] bf16 (2.25 MB).
__global__ __launch_bounds__(256)
void packw_kernel(const int* __restrict__ dflag,
                  const bf16* __restrict__ wx, const bf16* __restrict__ wy,
                  bf16* __restrict__ Wr)
{
    if (*dflag != 0) return;
    const int lin = blockIdx.x * 256 + threadIdx.x;   // gridDim.x = 1152 -> lin < 294912
    const int ci4 = lin & 63;
    const int m   = (lin >> 6) & 511;
    const int kk  = lin >> 15;                         // 0..8
    const int o   = m >> 1;
    const bf16* src = (m & 1) ? wy : wx;
    bf16 tmp[4];
    #pragma unroll
    for (int j = 0; j < 4; ++j)
        tmp[j] = src[(size_t)o * 2304 + (ci4 * 4 + j) * 9 + kk];
    *(uint2*)(Wr + ((size_t)kk * 512 + m) * CC + ci4 * 4) = *(const uint2*)tmp;
}

// ---------------- K1 (bf16): Sobel as implicit-GEMM MFMA ----------------
// M = 512 (oc x {gx,gy} interleaved), N = 64 (one image row y), K = 9*256.
// Block: 256 thr / 4 waves, tile 64(M) x 64(N). grid (8, 64).
// Per K-step (offset kk, ci chunk of 32): stage A[64][32] (weights) and
// B[64][32] = xT rows shifted by (dy,dx) with border masking; 4 mfma/wave.
// Epilogue: LDS transpose -> BN -> magnitude -> coalesced bf16 stores.
__global__ __launch_bounds__(256)
void sobel_mfma_kernel(const int* __restrict__ dflag,
                       const bf16* __restrict__ xT,
                       const bf16* __restrict__ Wr,
                       const bf16* __restrict__ bnx,
                       const bf16* __restrict__ bny,
                       bf16* __restrict__ xf)
{
    if (*dflag != 0) return;
    const int mt = blockIdx.x;      // 0..7  (64 M-rows each)
    const int y  = blockIdx.y;      // 0..63 (image row)
    const int tid = threadIdx.x;
    const int w = tid >> 6, lane = tid & 63;
    const int wm = (w >> 1) * 32, wn = (w & 1) * 32;
    const int lr = lane & 15, q = lane >> 4;

    __shared__ char smem[18432];
    bf16* Asm = (bf16*)smem;                 // [64][40] (80B rows: 2-way banks, free)
    bf16* Bsm = Asm + 64 * 40;               // [64][40]
    float* eb = (float*)smem;                // [64][72] epilogue reuse

    f32x4v acc[2][2];
    #pragma unroll
    for (int i = 0; i < 2; ++i)
        #pragma unroll
        for (int j = 0; j < 2; ++j) acc[i][j] = (f32x4v){0.f, 0.f, 0.f, 0.f};

    const int r = tid >> 2, ch = tid & 3;    // staging: row r, 16B chunk ch
    const bf16* Arow = Wr + (size_t)(mt * 64 + r) * CC + ch * 8;

    for (int kk = 0; kk < 9; ++kk) {
        const int dy = kk / 3 - 1, dx = kk - (kk / 3) * 3 - 1;
        const int ys = y + dy, xs = r + dx;
        const bool ok = (ys >= 0) && (ys < HH) && (xs >= 0) && (xs < WW);
        const bf16* Brow = xT + (size_t)(ys * WW + xs) * CC + ch * 8;
        const bf16* Ak = Arow + (size_t)kk * (512 * CC);
        for (int c0 = 0; c0 < CC; c0 += 32) {
            uint4 av = *(const uint4*)(Ak + c0);
            uint4 bv = make_uint4(0u, 0u, 0u, 0u);
            if (ok) bv = *(const uint4*)(Brow + c0);
            __syncthreads();                  // prev iteration's frag reads done
            *(uint4*)&Asm[r * 40 + ch * 8] = av;
            *(uint4*)&Bsm[r * 40 + ch * 8] = bv;
            __syncthreads();
            bf16x8v a0 = *(const bf16x8v*)&Asm[(wm + lr) * 40 + q * 8];
            bf16x8v a1 = *(const bf16x8v*)&Asm[(wm + 16 + lr) * 40 + q * 8];
            bf16x8v b0 = *(const bf16x8v*)&Bsm[(wn + lr) * 40 + q * 8];
            bf16x8v b1 = *(const bf16x8v*)&Bsm[(wn + 16 + lr) * 40 + q * 8];
            acc[0][0] = __builtin_amdgcn_mfma_f32_16x16x32_bf16(a0, b0, acc[0][0], 0, 0, 0);
            acc[0][1] = __builtin_amdgcn_mfma_f32_16x16x32_bf16(a0, b1, acc[0][1], 0, 0, 0);
            acc[1][0] = __builtin_amdgcn_mfma_f32_16x16x32_bf16(a1, b0, acc[1][0], 0, 0, 0);
            acc[1][1] = __builtin_amdgcn_mfma_f32_16x16x32_bf16(a1, b1, acc[1][1], 0, 0, 0);
        }
    }

    // ---- epilogue: C frags -> LDS [m_local][n], then BN + magnitude ----
    __syncthreads();
    #pragma unroll
    for (int fm = 0; fm < 2; ++fm)
        #pragma unroll
        for (int fn = 0; fn < 2; ++fn)
            #pragma unroll
            for (int reg = 0; reg < 4; ++reg)
                eb[(wm + fm * 16 + q * 4 + reg) * 72 + (wn + fn * 16 + lr)] = acc[fm][fn][reg];
    __syncthreads();
    {
        const int oc_l = tid >> 3, nch = tid & 7;
        const int oc = mt * 32 + oc_l;
        const float invx = b2f(bnx[oc]) * rsqrtf(b2f(bnx[3 * CC + oc]) + EPSF);
        const float bx   = b2f(bnx[CC + oc]);
        const float mx   = b2f(bnx[2 * CC + oc]);
        const float invy = b2f(bny[oc]) * rsqrtf(b2f(bny[3 * CC + oc]) + EPSF);
        const float by   = b2f(bny[CC + oc]);
        const float my   = b2f(bny[2 * CC + oc]);
        bf16 outv[8];
        #pragma unroll
        for (int j = 0; j < 8; ++j) {
            float gxv = eb[(2 * oc_l) * 72 + nch * 8 + j];
            float gyv = eb[(2 * oc_l + 1) * 72 + nch * 8 + j];
            float gxn = (gxv - mx) * invx + bx;
            float gyn = (gyv - my) * invy + by;
            outv[j] = f2b(sqrtf(gxn * gxn + gyn * gyn));
        }
        *(uint4*)(xf + (size_t)oc * NN + y * WW + nch * 8) = *(const uint4*)outv;
    }
}

// ---------------- K1 (f32 fallback): original Sobel conv3x3 + BN + magnitude ----------------
template<typename T>
__global__ __launch_bounds__(256)
void sobel_kernel(const int* __restrict__ dflag, int want,
                  const T* __restrict__ x1, const T* __restrict__ x2,
                  const T* __restrict__ wx1, const T* __restrict__ wy1,
                  const T* __restrict__ bnx1, const T* __restrict__ bny1,
                  const T* __restrict__ wx2, const T* __restrict__ wy2,
                  const T* __restrict__ bnx2, const T* __restrict__ bny2,
                  bf16* __restrict__ xf1, bf16* __restrict__ xf2)
{
    if (*dflag != want) return;
    const int z = blockIdx.z;
    const T* x   = z ? x2   : x1;
    const T* wx  = z ? wx2  : wx1;
    const T* wy  = z ? wy2  : wy1;
    const T* bnx = z ? bnx2 : bnx1;
    const T* bny = z ? bny2 : bny1;
    bf16* xf = z ? xf2 : xf1;

    const int tile = blockIdx.x;          // 0..3, 2x2 of 32x32
    const int ty0 = (tile >> 1) * 32;
    const int tx0 = (tile & 1) * 32;
    const int o0 = blockIdx.y * 8;

    const int tid = threadIdx.x;
    const int lx  = tid & 31;
    const int ly0 = (tid >> 5) * 4;       // 0..28 step 4

    __shared__ float xt[34 * 34];
    __shared__ float wl[8 * 20];

    float accx[8][4], accy[8][4];
    #pragma unroll
    for (int o = 0; o < 8; ++o)
        #pragma unroll
        for (int r = 0; r < 4; ++r) { accx[o][r] = 0.f; accy[o][r] = 0.f; }

    for (int ci = 0; ci < CC; ++ci) {
        for (int idx = tid; idx < 34 * 34; idx += 256) {
            int r = idx / 34, cc = idx - r * 34;
            int gy = ty0 + r - 1, gx = tx0 + cc - 1;
            float v = 0.f;
            if (gy >= 0 && gy < HH && gx >= 0 && gx < WW)
                v = ldf(x, (size_t)ci * NN + gy * WW + gx);
            xt[idx] = v;
        }
        if (tid < 144) {
            int o = tid / 18, k = tid - o * 18;
            const T* wsrc = (k < 9) ? wx : wy;
            wl[o * 20 + k] = ldf(wsrc, (size_t)((o0 + o) * CC + ci) * 9 + (k % 9));
        }
        __syncthreads();

        float xv[6][3];
        #pragma unroll
        for (int r = 0; r < 6; ++r)
            #pragma unroll
            for (int c = 0; c < 3; ++c)
                xv[r][c] = xt[(ly0 + r) * 34 + lx + c];

        #pragma unroll
        for (int o = 0; o < 8; ++o) {
            float w[18];
            #pragma unroll
            for (int k = 0; k < 18; ++k) w[k] = wl[o * 20 + k];
            #pragma unroll
            for (int pr = 0; pr < 4; ++pr) {
                float sx = 0.f, sy = 0.f;
                #pragma unroll
                for (int ky = 0; ky < 3; ++ky)
                    #pragma unroll
                    for (int kx = 0; kx < 3; ++kx) {
                        float xi = xv[pr + ky][kx];
                        sx = fmaf(w[ky * 3 + kx], xi, sx);
                        sy = fmaf(w[9 + ky * 3 + kx], xi, sy);
                    }
                accx[o][pr] += sx;
                accy[o][pr] += sy;
            }
        }
        __syncthreads();
    }

    #pragma unroll
    for (int o = 0; o < 8; ++o) {
        int oc = o0 + o;
        float invx = ldf(bnx, oc) * rsqrtf(ldf(bnx, 3 * CC + oc) + EPSF);
        float bx   = ldf(bnx, CC + oc);
        float mx   = ldf(bnx, 2 * CC + oc);
        float invy = ldf(bny, oc) * rsqrtf(ldf(bny, 3 * CC + oc) + EPSF);
        float by   = ldf(bny, CC + oc);
        float my   = ldf(bny, 2 * CC + oc);
        #pragma unroll
        for (int pr = 0; pr < 4; ++pr) {
            float gxn = (accx[o][pr] - mx) * invx + bx;
            float gyn = (accy[o][pr] - my) * invy + by;
            int py = ty0 + ly0 + pr, px = tx0 + lx;
            xf[oc * NN + py * WW + px] = f2b(sqrtf(gxn * gxn + gyn * gyn));
        }
    }
}

// ---------------- K2: 1x1 convs (q,k,v for both attends) ----------------
template<typename T>
__global__ __launch_bounds__(256)
void qkv_kernel(const int* __restrict__ dflag, int want,
                const T* __restrict__ x1, const T* __restrict__ x2,
                const bf16* __restrict__ xf1, const bf16* __restrict__ xf2,
                const T* __restrict__ q1w, const T* __restrict__ q1b,
                const T* __restrict__ k1w, const T* __restrict__ k1b,
                const T* __restrict__ v1w, const T* __restrict__ v1b,
                const T* __restrict__ q2w, const T* __restrict__ q2b,
                const T* __restrict__ k2w, const T* __restrict__ k2b,
                const T* __restrict__ v2w, const T* __restrict__ v2b,
                float* __restrict__ q1t, float* __restrict__ k1t, bf16* __restrict__ v1t,
                float* __restrict__ q2t, float* __restrict__ k2t, bf16* __restrict__ v2t)
{
    if (*dflag != want) return;
    const int z = blockIdx.z;
    const T* Wb; const T* bias;
    const T* Xt = nullptr; const bf16* Xb = nullptr;
    float* outF = nullptr; bf16* outB = nullptr; int O;
    switch (z) {
        case 0:  Wb = q1w; bias = q1b; Xt = x1;  outF = q1t; O = CQn; break;
        case 1:  Wb = k1w; bias = k1b; Xb = xf2; outF = k1t; O = CQn; break;
        case 2:  Wb = v1w; bias = v1b; Xb = xf2; outB = v1t; O = CC;  break;
        case 3:  Wb = q2w; bias = q2b; Xt = x2;  outF = q2t; O = CQn; break;
        case 4:  Wb = k2w; bias = k2b; Xb = xf1; outF = k2t; O = CQn; break;
        default: Wb = v2w; bias = v2b; Xb = xf1; outB = v2t; O = CC;  break;
    }
    const int o0 = blockIdx.x * 32;
    if (o0 >= O) return;
    const int n0 = blockIdx.y * 512;
    const int tid = threadIdx.x;

    __shared__ float lw[32 * 256];        // lw[o][c]
    for (int idx = tid; idx < 32 * 256; idx += 256)
        lw[idx] = ldf(Wb, (size_t)o0 * CC + idx);
    __syncthreads();

    const int n_a = n0 + tid;
    const int n_b = n0 + 256 + tid;

    float acca[32], accb[32];
    #pragma unroll
    for (int o = 0; o < 32; ++o) { acca[o] = 0.f; accb[o] = 0.f; }

    const float4* lw4 = (const float4*)lw;
    for (int c4 = 0; c4 < 64; ++c4) {
        float xa[4], xb[4];
        #pragma unroll
        for (int k = 0; k < 4; ++k) {
            size_t ia = (size_t)(c4 * 4 + k) * NN + n_a;
            size_t ib = (size_t)(c4 * 4 + k) * NN + n_b;
            if (Xt) { xa[k] = ldf(Xt, ia); xb[k] = ldf(Xt, ib); }
            else    { xa[k] = b2f(Xb[ia]); xb[k] = b2f(Xb[ib]); }
        }
        #pragma unroll
        for (int o = 0; o < 32; ++o) {
            float4 w4 = lw4[o * 64 + c4];
            acca[o] = fmaf(w4.x, xa[0], fmaf(w4.y, xa[1], fmaf(w4.z, xa[2], fmaf(w4.w, xa[3], acca[o]))));
            accb[o] = fmaf(w4.x, xb[0], fmaf(w4.y, xb[1], fmaf(w4.z, xb[2], fmaf(w4.w, xb[3], accb[o]))));
        }
    }
    #pragma unroll
    for (int o = 0; o < 32; ++o) {
        float bb = ldf(bias, o0 + o);
        acca[o] += bb; accb[o] += bb;
    }
    if (outF) {
        float* da = outF + (size_t)n_a * O + o0;
        float* db = outF + (size_t)n_b * O + o0;
        #pragma unroll
        for (int o4 = 0; o4 < 8; ++o4) {
            ((float4*)da)[o4] = make_float4(acca[o4*4], acca[o4*4+1], acca[o4*4+2], acca[o4*4+3]);
            ((float4*)db)[o4] = make_float4(accb[o4*4], accb[o4*4+1], accb[o4*4+2], accb[o4*4+3]);
        }
    } else {
        bf16* da = outB + (size_t)n_a * O + o0;
        bf16* db = outB + (size_t)n_b * O + o0;
        #pragma unroll
        for (int o = 0; o < 32; ++o) { da[o] = f2b(acca[o]); db[o] = f2b(accb[o]); }
    }
}

// ---------------- K3: flash attention (online softmax) ----------------
__device__ __forceinline__ void pv4(uint4 v, float ps0, float ps1,
                                    float* __restrict__ acc0, float* __restrict__ acc1)
{
    unsigned u[4] = { v.x, v.y, v.z, v.w };
    #pragma unroll
    for (int k = 0; k < 4; ++k) {
        float fl = __uint_as_float(u[k] << 16);
        float fh = __uint_as_float(u[k] & 0xffff0000u);
        acc0[2*k]   = fmaf(fl, ps0, acc0[2*k]);
        acc0[2*k+1] = fmaf(fh, ps0, acc0[2*k+1]);
        acc1[2*k]   = fmaf(fl, ps1, acc1[2*k]);
        acc1[2*k+1] = fmaf(fh, ps1, acc1[2*k+1]);
    }
}

template<typename T>
__global__ __launch_bounds__(256)
void attend_kernel(const int* __restrict__ dflag, int want,
                   const float* __restrict__ q1t, const float* __restrict__ k1t,
                   const bf16* __restrict__ v1t, const T* __restrict__ x1,
                   const T* __restrict__ g1,
                   const float* __restrict__ q2t, const float* __restrict__ k2t,
                   const bf16* __restrict__ v2t, const T* __restrict__ x2,
                   const T* __restrict__ g2,
                   T* __restrict__ out)
{
    if (*dflag != want) return;
    const int att = blockIdx.x >> 8;
    const int i0 = (blockIdx.x & 255) * 16;
    const float* qt = att ? q2t : q1t;
    const float* kt = att ? k2t : k1t;
    const bf16* vt  = att ? v2t : v1t;
    const T* xq = att ? x2 : x1;
    const T* gp = att ? g2 : g1;
    T* o = out + (size_t)att * CC * NN;

    const int tid = threadIdx.x;

    __shared__ float smem[4208];
    float* k_lds = smem;            // 64*36 = 2304
    float* p_lds = smem + 2304;     // 16*68 = 1088
    float* m_s   = smem + 4160;     // 16
    float* l_s   = smem + 4176;     // 16
    float* a_s   = smem + 4192;     // 16

    const int sq = tid >> 4, jg = tid & 15;   // softmax/QK mapping
    const int qg = tid >> 5, cl = tid & 31;   // PV mapping

    float4 qv[8];
    {
        const float4* qp = (const float4*)(qt + (size_t)(i0 + sq) * CQn);
        #pragma unroll
        for (int c4 = 0; c4 < 8; ++c4) qv[c4] = qp[c4];
    }

    if (tid < 16) { m_s[tid] = -INFINITY; l_s[tid] = 0.f; }

    float acc0[8], acc1[8];
    #pragma unroll
    for (int dc = 0; dc < 8; ++dc) { acc0[dc] = 0.f; acc1[dc] = 0.f; }

    for (int jt = 0; jt < 64; ++jt) {
        const int j0 = jt * 64;

        {
            const int j = tid >> 2, c8 = (tid & 3) * 8;
            const float4* src = (const float4*)(kt + (size_t)(j0 + j) * CQn + c8);
            float4 a = src[0], b = src[1];
            float4* dst = (float4*)(k_lds + j * 36 + c8);
            dst[0] = a; dst[1] = b;
        }
        __syncthreads();

        {
            float e[4];
            #pragma unroll
            for (int jj = 0; jj < 4; ++jj) {
                const float4* kr = (const float4*)(k_lds + (jj * 16 + jg) * 36);
                float s = 0.f;
                #pragma unroll
                for (int c4 = 0; c4 < 8; ++c4) {
                    float4 kv = kr[c4];
                    s = fmaf(qv[c4].x, kv.x, s);
                    s = fmaf(qv[c4].y, kv.y, s);
                    s = fmaf(qv[c4].z, kv.z, s);
                    s = fmaf(qv[c4].w, kv.w, s);
                }
                e[jj] = s;
            }
            float tm = fmaxf(fmaxf(e[0], e[1]), fmaxf(e[2], e[3]));
            #pragma unroll
            for (int msk = 1; msk <= 8; msk <<= 1)
                tm = fmaxf(tm, __shfl_xor(tm, msk));
            const float mo = m_s[sq];
            const float mn = fmaxf(mo, tm);
            float s = 0.f;
            #pragma unroll
            for (int jj = 0; jj < 4; ++jj) {
                float p = __expf(e[jj] - mn);
                p_lds[sq * 68 + jj * 16 + jg] = p;
                s += p;
            }
            #pragma unroll
            for (int msk = 1; msk <= 8; msk <<= 1)
                s += __shfl_xor(s, msk);
            if (jg == 0) {
                float alpha = __expf(mo - mn);
                a_s[sq] = alpha;
                m_s[sq] = mn;
                l_s[sq] = l_s[sq] * alpha + s;
            }
        }
        __syncthreads();

        {
            const float a0 = a_s[qg * 2 + 0], a1 = a_s[qg * 2 + 1];
            #pragma unroll
            for (int dc = 0; dc < 8; ++dc) { acc0[dc] *= a0; acc1[dc] *= a1; }
            const float* pr0 = p_lds + (qg * 2 + 0) * 68;
            const float* pr1 = p_lds + (qg * 2 + 1) * 68;
            const bf16* vb = vt + (size_t)j0 * CC + cl * 8;
            #pragma unroll 4
            for (int j4 = 0; j4 < 16; ++j4) {
                const float4 p0 = *(const float4*)(pr0 + j4 * 4);
                const float4 p1 = *(const float4*)(pr1 + j4 * 4);
                uint4 v[4];
                #pragma unroll
                for (int u = 0; u < 4; ++u)
                    v[u] = *(const uint4*)(vb + (size_t)(j4 * 4 + u) * CC);
                pv4(v[0], p0.x, p1.x, acc0, acc1);
                pv4(v[1], p0.y, p1.y, acc0, acc1);
                pv4(v[2], p0.z, p1.z, acc0, acc1);
                pv4(v[3], p0.w, p1.w, acc0, acc1);
            }
        }
    }

    __syncthreads();
    float* ot = smem;             // [16][260]
    #pragma unroll
    for (int dc = 0; dc < 8; ++dc) {
        ot[(qg * 2 + 0) * 260 + cl * 8 + dc] = acc0[dc];
        ot[(qg * 2 + 1) * 260 + cl * 8 + dc] = acc1[dc];
    }
    __syncthreads();
    {
        const float g = ldf(gp, 0);
        const int eq = tid & 15, cg = tid >> 4;
        const float rl = 1.0f / l_s[eq];
        #pragma unroll
        for (int i = 0; i < 16; ++i) {
            const int c = cg * 16 + i;
            float v = ot[eq * 260 + c];
            float xv = ldf(xq, (size_t)c * NN + i0 + eq);
            stf(o, (size_t)c * NN + i0 + eq, fmaf(g, v * rl, xv));
        }
    }
}

extern "C" void kernel_launch(void* const* d_in, const int* in_sizes, int n_in,
                              void* d_out, int out_size, void* d_ws, size_t ws_size,
                              hipStream_t stream) {
    // workspace: 256B flag header + 10.0 MB buffers (ws_size >= 11MB proven earlier).
    // Layout: xf1(2M) xf2(2M) | union region (6M):
    //   sobel phase : xT(2M) Wr(2.25M)          (read before qkv runs)
    //   post-sobel  : v1t(2M) v2t(2M) q1t k1t q2t k2t (0.5M each)
    if (ws_size < (size_t)(10 * 1024 * 1024 + 512 * 1024)) return;

    int* dflag = (int*)d_ws;
    char* base = (char*)d_ws + 256;
    bf16* xf1 = (bf16*)base;               // 2 MB
    bf16* xf2 = xf1 + 1048576;             // 2 MB
    char* ubase = (char*)(xf2 + 1048576);  // 6 MB union region
    bf16* xTb = (bf16*)ubase;                          // 2 MB   [4096][256]
    bf16* Wrb = (bf16*)(ubase + 2 * 1024 * 1024);      // 2.25 MB [9][512][256]
    bf16* v1t = (bf16*)ubase;              // 2 MB (after sobel)
    bf16* v2t = v1t + 1048576;             // 2 MB
    float* q1t = (float*)(v2t + 1048576);  // 0.5 MB
    float* k1t = q1t + 131072;             // 0.5 MB
    float* q2t = k1t + 131072;             // 0.5 MB
    float* k2t = q2t + 131072;             // 0.5 MB

    detect_kernel<<<dim3(1), 256, 0, stream>>>((const unsigned short*)d_in[0], dflag);

    // ---- bf16 pipeline (want=0): MFMA sobel, image 0 then image 1 sharing xT/Wr ----
    {
        typedef bf16 T;
        transpose_kernel<<<dim3(4, 64), 256, 0, stream>>>(dflag, (const T*)d_in[0], xTb);
        packw_kernel<<<dim3(1152), 256, 0, stream>>>(dflag, (const T*)d_in[2], (const T*)d_in[3], Wrb);
        sobel_mfma_kernel<<<dim3(8, 64), 256, 0, stream>>>(dflag, xTb, Wrb,
            (const T*)d_in[4], (const T*)d_in[5], xf1);
        transpose_kernel<<<dim3(4, 64), 256, 0, stream>>>(dflag, (const T*)d_in[1], xTb);
        packw_kernel<<<dim3(1152), 256, 0, stream>>>(dflag, (const T*)d_in[6], (const T*)d_in[7], Wrb);
        sobel_mfma_kernel<<<dim3(8, 64), 256, 0, stream>>>(dflag, xTb, Wrb,
            (const T*)d_in[8], (const T*)d_in[9], xf2);
        qkv_kernel<T><<<dim3(8, 8, 6), 256, 0, stream>>>(dflag, 0,
            (const T*)d_in[0], (const T*)d_in[1], xf1, xf2,
            (const T*)d_in[10], (const T*)d_in[11], (const T*)d_in[12], (const T*)d_in[13],
            (const T*)d_in[14], (const T*)d_in[15], (const T*)d_in[16], (const T*)d_in[17],
            (const T*)d_in[18], (const T*)d_in[19], (const T*)d_in[20], (const T*)d_in[21],
            q1t, k1t, v1t, q2t, k2t, v2t);
        attend_kernel<T><<<dim3(512), 256, 0, stream>>>(dflag, 0,
            q1t, k1t, v1t, (const T*)d_in[0], (const T*)d_in[22],
            q2t, k2t, v2t, (const T*)d_in[1], (const T*)d_in[23],
            (T*)d_out);
    }
    // ---- f32 pipeline (want=1), unchanged fallback ----
    {
        typedef float T;
        sobel_kernel<T><<<dim3(4, 32, 2), 256, 0, stream>>>(dflag, 1,
            (const T*)d_in[0], (const T*)d_in[1],
            (const T*)d_in[2], (const T*)d_in[3], (const T*)d_in[4], (const T*)d_in[5],
            (const T*)d_in[6], (const T*)d_in[7], (const T*)d_in[8], (const T*)d_in[9],
            xf1, xf2);
        qkv_kernel<T><<<dim3(8, 8, 6), 256, 0, stream>>>(dflag, 1,
            (const T*)d_in[0], (const T*)d_in[1], xf1, xf2,
            (const T*)d_in[10], (const T*)d_in[11], (const T*)d_in[12], (const T*)d_in[13],
            (const T*)d_in[14], (const T*)d_in[15], (const T*)d_in[16], (const T*)d_in[17],
            (const T*)d_in[18], (const T*)d_in[19], (const T*)d_in[20], (const T*)d_in[21],
            q1t, k1t, v1t, q2t, k2t, v2t);
        attend_kernel<T><<<dim3(512), 256, 0, stream>>>(dflag, 1,
            q1t, k1t, v1t, (const T*)d_in[0], (const T*)d_in[22],
            q2t, k2t, v2t, (const T*)d_in[1], (const T*)d_in[23],
            (T*)d_out);
    }
}

// Round 3
// 881.485 us; speedup vs baseline: 1.7283x; 1.7283x over previous
//
#include <hip/hip_runtime.h>
#include <hip/hip_bf16.h>
#include <math.h>

#define CC 256
#define CQn 32
#define HH 64
#define WW 64
#define NN 4096
#define EPSF 1e-5f

typedef __hip_bfloat16 bf16;

typedef __attribute__((ext_vector_type(8))) short bf16x8v;
typedef __attribute__((ext_vector_type(4))) float f32x4v;

__device__ __forceinline__ float b2f(bf16 v) { return __bfloat162float(v); }
__device__ __forceinline__ bf16 f2b(float v) { return __float2bfloat16(v); }

template<typename T> __device__ __forceinline__ float ldf(const T* p, size_t i);
template<> __device__ __forceinline__ float ldf<float>(const float* p, size_t i) { return p[i]; }
template<> __device__ __forceinline__ float ldf<bf16>(const bf16* p, size_t i)  { return b2f(p[i]); }

__device__ __forceinline__ void stf(float* p, size_t i, float v) { p[i] = v; }
__device__ __forceinline__ void stf(bf16* p, size_t i, float v)  { p[i] = f2b(v); }

// ---------------- K0: dtype detector ----------------
// flag: 0 = data is bf16, 1 = data is f32. (Counters prove the harness data
// is f32: the f32 pipeline's kernels are the ones with real durations.)
__global__ __launch_bounds__(256)
void detect_kernel(const unsigned short* __restrict__ x1, int* __restrict__ flag)
{
    __shared__ int bad;
    if (threadIdx.x == 0) bad = 0;
    __syncthreads();
    int mybad = 0;
    for (int i = threadIdx.x; i < 16384; i += 256) {
        unsigned short u = x1[i];
        if ((u & 0x7F80u) == 0x7F80u) mybad = 1;
    }
    if (mybad) atomicOr(&bad, 1);
    __syncthreads();
    if (threadIdx.x == 0) *flag = bad ? 1 : 0;
}

// ---------------- bf16 path prep 1: x [256][4096] -> xT [4096][256] ----------------
__global__ __launch_bounds__(256)
void transpose_kernel(const int* __restrict__ dflag,
                      const bf16* __restrict__ x, bf16* __restrict__ xT)
{
    if (*dflag != 0) return;
    const int ci0 = blockIdx.x * 64;   // gridDim.x = 4
    const int p0  = blockIdx.y * 64;   // gridDim.y = 64
    const int t = threadIdx.x;
    const int r0 = t >> 3;             // 0..31
    const int ch = t & 7;              // 8 chunks of 8 bf16

    __shared__ bf16 tile[64][72];

    #pragma unroll
    for (int pass = 0; pass < 2; ++pass) {
        int r = pass * 32 + r0;
        uint4 v = *(const uint4*)(x + (size_t)(ci0 + r) * NN + p0 + ch * 8);
        *(uint4*)&tile[r][ch * 8] = v;
    }
    __syncthreads();
    #pragma unroll
    for (int pass = 0; pass < 2; ++pass) {
        int p = pass * 32 + r0;
        bf16 tmp[8];
        #pragma unroll
        for (int j = 0; j < 8; ++j) tmp[j] = tile[ch * 8 + j][p];
        *(uint4*)(xT + (size_t)(p0 + p) * CC + ci0 + ch * 8) = *(const uint4*)tmp;
    }
}

// ---------------- bf16 path prep 2: weights -> Wr[kk][m][ci], m = 2*o + isY ----------------
__global__ __launch_bounds__(256)
void packw_kernel(const int* __restrict__ dflag,
                  const bf16* __restrict__ wx, const bf16* __restrict__ wy,
                  bf16* __restrict__ Wr)
{
    if (*dflag != 0) return;
    const int lin = blockIdx.x * 256 + threadIdx.x;
    const int ci4 = lin & 63;
    const int m   = (lin >> 6) & 511;
    const int kk  = lin >> 15;                         // 0..8
    const int o   = m >> 1;
    const bf16* src = (m & 1) ? wy : wx;
    bf16 tmp[4];
    #pragma unroll
    for (int j = 0; j < 4; ++j)
        tmp[j] = src[(size_t)o * 2304 + (ci4 * 4 + j) * 9 + kk];
    *(uint2*)(Wr + ((size_t)kk * 512 + m) * CC + ci4 * 4) = *(const uint2*)tmp;
}

// ---------------- K1 (bf16): Sobel as implicit-GEMM MFMA ----------------
__global__ __launch_bounds__(256)
void sobel_mfma_kernel(const int* __restrict__ dflag,
                       const bf16* __restrict__ xT,
                       const bf16* __restrict__ Wr,
                       const bf16* __restrict__ bnx,
                       const bf16* __restrict__ bny,
                       bf16* __restrict__ xf)
{
    if (*dflag != 0) return;
    const int mt = blockIdx.x;      // 0..7
    const int y  = blockIdx.y;      // 0..63
    const int tid = threadIdx.x;
    const int w = tid >> 6, lane = tid & 63;
    const int wm = (w >> 1) * 32, wn = (w & 1) * 32;
    const int lr = lane & 15, q = lane >> 4;

    __shared__ char smem[18432];
    bf16* Asm = (bf16*)smem;                 // [64][40]
    bf16* Bsm = Asm + 64 * 40;               // [64][40]
    float* eb = (float*)smem;                // [64][72] epilogue reuse

    f32x4v acc[2][2];
    #pragma unroll
    for (int i = 0; i < 2; ++i)
        #pragma unroll
        for (int j = 0; j < 2; ++j) acc[i][j] = (f32x4v){0.f, 0.f, 0.f, 0.f};

    const int r = tid >> 2, ch = tid & 3;
    const bf16* Arow = Wr + (size_t)(mt * 64 + r) * CC + ch * 8;

    for (int kk = 0; kk < 9; ++kk) {
        const int dy = kk / 3 - 1, dx = kk - (kk / 3) * 3 - 1;
        const int ys = y + dy, xs = r + dx;
        const bool ok = (ys >= 0) && (ys < HH) && (xs >= 0) && (xs < WW);
        const bf16* Brow = xT + (size_t)(ys * WW + xs) * CC + ch * 8;
        const bf16* Ak = Arow + (size_t)kk * (512 * CC);
        for (int c0 = 0; c0 < CC; c0 += 32) {
            uint4 av = *(const uint4*)(Ak + c0);
            uint4 bv = make_uint4(0u, 0u, 0u, 0u);
            if (ok) bv = *(const uint4*)(Brow + c0);
            __syncthreads();
            *(uint4*)&Asm[r * 40 + ch * 8] = av;
            *(uint4*)&Bsm[r * 40 + ch * 8] = bv;
            __syncthreads();
            bf16x8v a0 = *(const bf16x8v*)&Asm[(wm + lr) * 40 + q * 8];
            bf16x8v a1 = *(const bf16x8v*)&Asm[(wm + 16 + lr) * 40 + q * 8];
            bf16x8v b0 = *(const bf16x8v*)&Bsm[(wn + lr) * 40 + q * 8];
            bf16x8v b1 = *(const bf16x8v*)&Bsm[(wn + 16 + lr) * 40 + q * 8];
            acc[0][0] = __builtin_amdgcn_mfma_f32_16x16x32_bf16(a0, b0, acc[0][0], 0, 0, 0);
            acc[0][1] = __builtin_amdgcn_mfma_f32_16x16x32_bf16(a0, b1, acc[0][1], 0, 0, 0);
            acc[1][0] = __builtin_amdgcn_mfma_f32_16x16x32_bf16(a1, b0, acc[1][0], 0, 0, 0);
            acc[1][1] = __builtin_amdgcn_mfma_f32_16x16x32_bf16(a1, b1, acc[1][1], 0, 0, 0);
        }
    }

    __syncthreads();
    #pragma unroll
    for (int fm = 0; fm < 2; ++fm)
        #pragma unroll
        for (int fn = 0; fn < 2; ++fn)
            #pragma unroll
            for (int reg = 0; reg < 4; ++reg)
                eb[(wm + fm * 16 + q * 4 + reg) * 72 + (wn + fn * 16 + lr)] = acc[fm][fn][reg];
    __syncthreads();
    {
        const int oc_l = tid >> 3, nch = tid & 7;
        const int oc = mt * 32 + oc_l;
        const float invx = b2f(bnx[oc]) * rsqrtf(b2f(bnx[3 * CC + oc]) + EPSF);
        const float bx   = b2f(bnx[CC + oc]);
        const float mx   = b2f(bnx[2 * CC + oc]);
        const float invy = b2f(bny[oc]) * rsqrtf(b2f(bny[3 * CC + oc]) + EPSF);
        const float by   = b2f(bny[CC + oc]);
        const float my   = b2f(bny[2 * CC + oc]);
        bf16 outv[8];
        #pragma unroll
        for (int j = 0; j < 8; ++j) {
            float gxv = eb[(2 * oc_l) * 72 + nch * 8 + j];
            float gyv = eb[(2 * oc_l + 1) * 72 + nch * 8 + j];
            float gxn = (gxv - mx) * invx + bx;
            float gyn = (gyv - my) * invy + by;
            outv[j] = f2b(sqrtf(gxn * gxn + gyn * gyn));
        }
        *(uint4*)(xf + (size_t)oc * NN + y * WW + nch * 8) = *(const uint4*)outv;
    }
}

// ---------------- f32 path prep: x f32 [256][4096] -> xT_hi + xT_lo bf16 [4096][256] ----------------
// x = hi + lo with hi = bf16(x), lo = bf16(x - hi): exact to ~2^-17 relative.
__global__ __launch_bounds__(256)
void transpose_split_kernel(const int* __restrict__ dflag,
                            const float* __restrict__ x,
                            bf16* __restrict__ xT_hi, bf16* __restrict__ xT_lo)
{
    if (*dflag != 1) return;
    const int ci0 = blockIdx.x * 64;   // 4
    const int p0  = blockIdx.y * 64;   // 64
    const int t = threadIdx.x;
    const int r = t >> 2, ch = t & 3;

    __shared__ float tile[64][76];     // 76: keeps float4 rows 16B-aligned

    {
        const float* src = x + (size_t)(ci0 + r) * NN + p0 + ch * 16;
        #pragma unroll
        for (int i = 0; i < 4; ++i) {
            float4 v = *(const float4*)(src + i * 4);
            *(float4*)&tile[r][ch * 16 + i * 4] = v;
        }
    }
    __syncthreads();
    {
        bf16 hi[16], lo[16];
        #pragma unroll
        for (int j = 0; j < 16; ++j) {
            float v = tile[ch * 16 + j][r];
            bf16 h = f2b(v);
            hi[j] = h;
            lo[j] = f2b(v - b2f(h));
        }
        size_t base = (size_t)(p0 + r) * CC + ci0 + ch * 16;
        *(uint4*)(xT_hi + base)     = ((const uint4*)hi)[0];
        *(uint4*)(xT_hi + base + 8) = ((const uint4*)hi)[1];
        *(uint4*)(xT_lo + base)     = ((const uint4*)lo)[0];
        *(uint4*)(xT_lo + base + 8) = ((const uint4*)lo)[1];
    }
}

// ---------------- K1 (f32): Sobel as split-precision implicit-GEMM MFMA ----------------
// D = sum(w_hi*x_hi + w_hi*x_lo + w_lo*x_hi)  (lo*lo term ~2^-18, dropped).
// w split in-kernel from raw f32 weights (contiguous 24-float runs per thread).
// B staged once per (dy,c0) into a [66][40] halo tile; dx is a frag-read row offset.
__global__ __launch_bounds__(256)
void sobel_mfma_f32_kernel(const int* __restrict__ dflag,
                           const bf16* __restrict__ xTh,
                           const bf16* __restrict__ xTl,
                           const float* __restrict__ wx,
                           const float* __restrict__ wy,
                           const float* __restrict__ bnx,
                           const float* __restrict__ bny,
                           bf16* __restrict__ xf)
{
    if (*dflag != 1) return;
    const int mt = blockIdx.x;      // 0..7  (64 M-rows each; m = 2*oc + isY)
    const int y  = blockIdx.y;      // 0..63 (image row)
    const int tid = threadIdx.x;
    const int w = tid >> 6, lane = tid & 63;
    const int wm = (w >> 1) * 32, wn = (w & 1) * 32;
    const int lr = lane & 15, q = lane >> 4;

    __shared__ char smem[20800];
    bf16* Ah = (bf16*)smem;          // [64][40] w_hi   (80B rows: 2-way banks, free)
    bf16* Al = Ah + 2560;            // [64][40] w_lo
    bf16* Bh = Al + 2560;            // [66][40] x_hi, halo rows 0 and 65 stay zero
    bf16* Bl = Bh + 2640;            // [66][40] x_lo
    float* eb = (float*)smem;        // [64][72] epilogue reuse

    f32x4v acc[2][2];
    #pragma unroll
    for (int i = 0; i < 2; ++i)
        #pragma unroll
        for (int j = 0; j < 2; ++j) acc[i][j] = (f32x4v){0.f, 0.f, 0.f, 0.f};

    const int r = tid >> 2, ch = tid & 3;    // staging: row r, 8-elem chunk ch
    const int o = mt * 32 + (r >> 1);
    const float* wbase = ((r & 1) ? wy : wx) + (size_t)o * 2304;

    // zero B halo rows (xs = -1 and xs = 64); never rewritten in the loop
    if (tid < 40) {
        Bh[tid] = f2b(0.f);           Bl[tid] = f2b(0.f);
        Bh[65 * 40 + tid] = f2b(0.f); Bl[65 * 40 + tid] = f2b(0.f);
    }

    for (int c0i = 0; c0i < 8; ++c0i) {
        const int c0 = c0i * 32;
        for (int dy = 0; dy < 3; ++dy) {
            const int ys = y + dy - 1;
            // 24 contiguous-ish w floats: this thread's 8 ci x 3 dx for row dy
            const float* wb = wbase + (size_t)(c0 + ch * 8) * 9 + dy * 3;
            float wv[8][3];
            #pragma unroll
            for (int j = 0; j < 8; ++j)
                #pragma unroll
                for (int d = 0; d < 3; ++d)
                    wv[j][d] = wb[j * 9 + d];
            // B values for (ys, xs=r), ci chunk
            uint4 bh = make_uint4(0u, 0u, 0u, 0u), bl = make_uint4(0u, 0u, 0u, 0u);
            if (ys >= 0 && ys < HH) {
                size_t bidx = (size_t)(ys * WW + r) * CC + c0 + ch * 8;
                bh = *(const uint4*)(xTh + bidx);
                bl = *(const uint4*)(xTl + bidx);
            }
            #pragma unroll
            for (int d = 0; d < 3; ++d) {
                __syncthreads();              // prior frag reads done
                {
                    bf16 ah8[8], al8[8];
                    #pragma unroll
                    for (int j = 0; j < 8; ++j) {
                        float v = wv[j][d];
                        bf16 h = f2b(v);
                        ah8[j] = h;
                        al8[j] = f2b(v - b2f(h));
                    }
                    *(uint4*)&Ah[r * 40 + ch * 8] = *(const uint4*)ah8;
                    *(uint4*)&Al[r * 40 + ch * 8] = *(const uint4*)al8;
                    if (d == 0) {
                        *(uint4*)&Bh[(r + 1) * 40 + ch * 8] = bh;
                        *(uint4*)&Bl[(r + 1) * 40 + ch * 8] = bl;
                    }
                }
                __syncthreads();
                bf16x8v ah0 = *(const bf16x8v*)&Ah[(wm + lr) * 40 + q * 8];
                bf16x8v ah1 = *(const bf16x8v*)&Ah[(wm + 16 + lr) * 40 + q * 8];
                bf16x8v al0 = *(const bf16x8v*)&Al[(wm + lr) * 40 + q * 8];
                bf16x8v al1 = *(const bf16x8v*)&Al[(wm + 16 + lr) * 40 + q * 8];
                const int b0r = wn + lr + d, b1r = wn + 16 + lr + d;  // halo shift
                bf16x8v bh0 = *(const bf16x8v*)&Bh[b0r * 40 + q * 8];
                bf16x8v bh1 = *(const bf16x8v*)&Bh[b1r * 40 + q * 8];
                bf16x8v bl0 = *(const bf16x8v*)&Bl[b0r * 40 + q * 8];
                bf16x8v bl1 = *(const bf16x8v*)&Bl[b1r * 40 + q * 8];
                acc[0][0] = __builtin_amdgcn_mfma_f32_16x16x32_bf16(ah0, bh0, acc[0][0], 0, 0, 0);
                acc[0][0] = __builtin_amdgcn_mfma_f32_16x16x32_bf16(ah0, bl0, acc[0][0], 0, 0, 0);
                acc[0][0] = __builtin_amdgcn_mfma_f32_16x16x32_bf16(al0, bh0, acc[0][0], 0, 0, 0);
                acc[0][1] = __builtin_amdgcn_mfma_f32_16x16x32_bf16(ah0, bh1, acc[0][1], 0, 0, 0);
                acc[0][1] = __builtin_amdgcn_mfma_f32_16x16x32_bf16(ah0, bl1, acc[0][1], 0, 0, 0);
                acc[0][1] = __builtin_amdgcn_mfma_f32_16x16x32_bf16(al0, bh1, acc[0][1], 0, 0, 0);
                acc[1][0] = __builtin_amdgcn_mfma_f32_16x16x32_bf16(ah1, bh0, acc[1][0], 0, 0, 0);
                acc[1][0] = __builtin_amdgcn_mfma_f32_16x16x32_bf16(ah1, bl0, acc[1][0], 0, 0, 0);
                acc[1][0] = __builtin_amdgcn_mfma_f32_16x16x32_bf16(al1, bh0, acc[1][0], 0, 0, 0);
                acc[1][1] = __builtin_amdgcn_mfma_f32_16x16x32_bf16(ah1, bh1, acc[1][1], 0, 0, 0);
                acc[1][1] = __builtin_amdgcn_mfma_f32_16x16x32_bf16(ah1, bl1, acc[1][1], 0, 0, 0);
                acc[1][1] = __builtin_amdgcn_mfma_f32_16x16x32_bf16(al1, bh1, acc[1][1], 0, 0, 0);
            }
        }
    }

    // ---- epilogue: C frags -> LDS [m_local][n], then BN + magnitude ----
    __syncthreads();
    #pragma unroll
    for (int fm = 0; fm < 2; ++fm)
        #pragma unroll
        for (int fn = 0; fn < 2; ++fn)
            #pragma unroll
            for (int reg = 0; reg < 4; ++reg)
                eb[(wm + fm * 16 + q * 4 + reg) * 72 + (wn + fn * 16 + lr)] = acc[fm][fn][reg];
    __syncthreads();
    {
        const int oc_l = tid >> 3, nch = tid & 7;
        const int oc = mt * 32 + oc_l;
        const float invx = bnx[oc] * rsqrtf(bnx[3 * CC + oc] + EPSF);
        const float bx   = bnx[CC + oc];
        const float mx   = bnx[2 * CC + oc];
        const float invy = bny[oc] * rsqrtf(bny[3 * CC + oc] + EPSF);
        const float by   = bny[CC + oc];
        const float my   = bny[2 * CC + oc];
        bf16 outv[8];
        #pragma unroll
        for (int j = 0; j < 8; ++j) {
            float gxv = eb[(2 * oc_l) * 72 + nch * 8 + j];
            float gyv = eb[(2 * oc_l + 1) * 72 + nch * 8 + j];
            float gxn = (gxv - mx) * invx + bx;
            float gyn = (gyv - my) * invy + by;
            outv[j] = f2b(sqrtf(gxn * gxn + gyn * gyn));
        }
        *(uint4*)(xf + (size_t)oc * NN + y * WW + nch * 8) = *(const uint4*)outv;
    }
}

// ---------------- K2: 1x1 convs (q,k,v for both attends) ----------------
template<typename T>
__global__ __launch_bounds__(256)
void qkv_kernel(const int* __restrict__ dflag, int want,
                const T* __restrict__ x1, const T* __restrict__ x2,
                const bf16* __restrict__ xf1, const bf16* __restrict__ xf2,
                const T* __restrict__ q1w, const T* __restrict__ q1b,
                const T* __restrict__ k1w, const T* __restrict__ k1b,
                const T* __restrict__ v1w, const T* __restrict__ v1b,
                const T* __restrict__ q2w, const T* __restrict__ q2b,
                const T* __restrict__ k2w, const T* __restrict__ k2b,
                const T* __restrict__ v2w, const T* __restrict__ v2b,
                float* __restrict__ q1t, float* __restrict__ k1t, bf16* __restrict__ v1t,
                float* __restrict__ q2t, float* __restrict__ k2t, bf16* __restrict__ v2t)
{
    if (*dflag != want) return;
    const int z = blockIdx.z;
    const T* Wb; const T* bias;
    const T* Xt = nullptr; const bf16* Xb = nullptr;
    float* outF = nullptr; bf16* outB = nullptr; int O;
    switch (z) {
        case 0:  Wb = q1w; bias = q1b; Xt = x1;  outF = q1t; O = CQn; break;
        case 1:  Wb = k1w; bias = k1b; Xb = xf2; outF = k1t; O = CQn; break;
        case 2:  Wb = v1w; bias = v1b; Xb = xf2; outB = v1t; O = CC;  break;
        case 3:  Wb = q2w; bias = q2b; Xt = x2;  outF = q2t; O = CQn; break;
        case 4:  Wb = k2w; bias = k2b; Xb = xf1; outF = k2t; O = CQn; break;
        default: Wb = v2w; bias = v2b; Xb = xf1; outB = v2t; O = CC;  break;
    }
    const int o0 = blockIdx.x * 32;
    if (o0 >= O) return;
    const int n0 = blockIdx.y * 512;
    const int tid = threadIdx.x;

    __shared__ float lw[32 * 256];        // lw[o][c]
    for (int idx = tid; idx < 32 * 256; idx += 256)
        lw[idx] = ldf(Wb, (size_t)o0 * CC + idx);
    __syncthreads();

    const int n_a = n0 + tid;
    const int n_b = n0 + 256 + tid;

    float acca[32], accb[32];
    #pragma unroll
    for (int o = 0; o < 32; ++o) { acca[o] = 0.f; accb[o] = 0.f; }

    const float4* lw4 = (const float4*)lw;
    for (int c4 = 0; c4 < 64; ++c4) {
        float xa[4], xb[4];
        #pragma unroll
        for (int k = 0; k < 4; ++k) {
            size_t ia = (size_t)(c4 * 4 + k) * NN + n_a;
            size_t ib = (size_t)(c4 * 4 + k) * NN + n_b;
            if (Xt) { xa[k] = ldf(Xt, ia); xb[k] = ldf(Xt, ib); }
            else    { xa[k] = b2f(Xb[ia]); xb[k] = b2f(Xb[ib]); }
        }
        #pragma unroll
        for (int o = 0; o < 32; ++o) {
            float4 w4 = lw4[o * 64 + c4];
            acca[o] = fmaf(w4.x, xa[0], fmaf(w4.y, xa[1], fmaf(w4.z, xa[2], fmaf(w4.w, xa[3], acca[o]))));
            accb[o] = fmaf(w4.x, xb[0], fmaf(w4.y, xb[1], fmaf(w4.z, xb[2], fmaf(w4.w, xb[3], accb[o]))));
        }
    }
    #pragma unroll
    for (int o = 0; o < 32; ++o) {
        float bb = ldf(bias, o0 + o);
        acca[o] += bb; accb[o] += bb;
    }
    if (outF) {
        float* da = outF + (size_t)n_a * O + o0;
        float* db = outF + (size_t)n_b * O + o0;
        #pragma unroll
        for (int o4 = 0; o4 < 8; ++o4) {
            ((float4*)da)[o4] = make_float4(acca[o4*4], acca[o4*4+1], acca[o4*4+2], acca[o4*4+3]);
            ((float4*)db)[o4] = make_float4(accb[o4*4], accb[o4*4+1], accb[o4*4+2], accb[o4*4+3]);
        }
    } else {
        bf16* da = outB + (size_t)n_a * O + o0;
        bf16* db = outB + (size_t)n_b * O + o0;
        #pragma unroll
        for (int o = 0; o < 32; ++o) { da[o] = f2b(acca[o]); db[o] = f2b(accb[o]); }
    }
}

// ---------------- K3: flash attention (online softmax) ----------------
__device__ __forceinline__ void pv4(uint4 v, float ps0, float ps1,
                                    float* __restrict__ acc0, float* __restrict__ acc1)
{
    unsigned u[4] = { v.x, v.y, v.z, v.w };
    #pragma unroll
    for (int k = 0; k < 4; ++k) {
        float fl = __uint_as_float(u[k] << 16);
        float fh = __uint_as_float(u[k] & 0xffff0000u);
        acc0[2*k]   = fmaf(fl, ps0, acc0[2*k]);
        acc0[2*k+1] = fmaf(fh, ps0, acc0[2*k+1]);
        acc1[2*k]   = fmaf(fl, ps1, acc1[2*k]);
        acc1[2*k+1] = fmaf(fh, ps1, acc1[2*k+1]);
    }
}

template<typename T>
__global__ __launch_bounds__(256)
void attend_kernel(const int* __restrict__ dflag, int want,
                   const float* __restrict__ q1t, const float* __restrict__ k1t,
                   const bf16* __restrict__ v1t, const T* __restrict__ x1,
                   const T* __restrict__ g1,
                   const float* __restrict__ q2t, const float* __restrict__ k2t,
                   const bf16* __restrict__ v2t, const T* __restrict__ x2,
                   const T* __restrict__ g2,
                   T* __restrict__ out)
{
    if (*dflag != want) return;
    const int att = blockIdx.x >> 8;
    const int i0 = (blockIdx.x & 255) * 16;
    const float* qt = att ? q2t : q1t;
    const float* kt = att ? k2t : k1t;
    const bf16* vt  = att ? v2t : v1t;
    const T* xq = att ? x2 : x1;
    const T* gp = att ? g2 : g1;
    T* o = out + (size_t)att * CC * NN;

    const int tid = threadIdx.x;

    __shared__ float smem[4208];
    float* k_lds = smem;            // 64*36 = 2304
    float* p_lds = smem + 2304;     // 16*68 = 1088
    float* m_s   = smem + 4160;     // 16
    float* l_s   = smem + 4176;     // 16
    float* a_s   = smem + 4192;     // 16

    const int sq = tid >> 4, jg = tid & 15;   // softmax/QK mapping
    const int qg = tid >> 5, cl = tid & 31;   // PV mapping

    float4 qv[8];
    {
        const float4* qp = (const float4*)(qt + (size_t)(i0 + sq) * CQn);
        #pragma unroll
        for (int c4 = 0; c4 < 8; ++c4) qv[c4] = qp[c4];
    }

    if (tid < 16) { m_s[tid] = -INFINITY; l_s[tid] = 0.f; }

    float acc0[8], acc1[8];
    #pragma unroll
    for (int dc = 0; dc < 8; ++dc) { acc0[dc] = 0.f; acc1[dc] = 0.f; }

    for (int jt = 0; jt < 64; ++jt) {
        const int j0 = jt * 64;

        {
            const int j = tid >> 2, c8 = (tid & 3) * 8;
            const float4* src = (const float4*)(kt + (size_t)(j0 + j) * CQn + c8);
            float4 a = src[0], b = src[1];
            float4* dst = (float4*)(k_lds + j * 36 + c8);
            dst[0] = a; dst[1] = b;
        }
        __syncthreads();

        {
            float e[4];
            #pragma unroll
            for (int jj = 0; jj < 4; ++jj) {
                const float4* kr = (const float4*)(k_lds + (jj * 16 + jg) * 36);
                float s = 0.f;
                #pragma unroll
                for (int c4 = 0; c4 < 8; ++c4) {
                    float4 kv = kr[c4];
                    s = fmaf(qv[c4].x, kv.x, s);
                    s = fmaf(qv[c4].y, kv.y, s);
                    s = fmaf(qv[c4].z, kv.z, s);
                    s = fmaf(qv[c4].w, kv.w, s);
                }
                e[jj] = s;
            }
            float tm = fmaxf(fmaxf(e[0], e[1]), fmaxf(e[2], e[3]));
            #pragma unroll
            for (int msk = 1; msk <= 8; msk <<= 1)
                tm = fmaxf(tm, __shfl_xor(tm, msk));
            const float mo = m_s[sq];
            const float mn = fmaxf(mo, tm);
            float s = 0.f;
            #pragma unroll
            for (int jj = 0; jj < 4; ++jj) {
                float p = __expf(e[jj] - mn);
                p_lds[sq * 68 + jj * 16 + jg] = p;
                s += p;
            }
            #pragma unroll
            for (int msk = 1; msk <= 8; msk <<= 1)
                s += __shfl_xor(s, msk);
            if (jg == 0) {
                float alpha = __expf(mo - mn);
                a_s[sq] = alpha;
                m_s[sq] = mn;
                l_s[sq] = l_s[sq] * alpha + s;
            }
        }
        __syncthreads();

        {
            const float a0 = a_s[qg * 2 + 0], a1 = a_s[qg * 2 + 1];
            #pragma unroll
            for (int dc = 0; dc < 8; ++dc) { acc0[dc] *= a0; acc1[dc] *= a1; }
            const float* pr0 = p_lds + (qg * 2 + 0) * 68;
            const float* pr1 = p_lds + (qg * 2 + 1) * 68;
            const bf16* vb = vt + (size_t)j0 * CC + cl * 8;
            #pragma unroll 4
            for (int j4 = 0; j4 < 16; ++j4) {
                const float4 p0 = *(const float4*)(pr0 + j4 * 4);
                const float4 p1 = *(const float4*)(pr1 + j4 * 4);
                uint4 v[4];
                #pragma unroll
                for (int u = 0; u < 4; ++u)
                    v[u] = *(const uint4*)(vb + (size_t)(j4 * 4 + u) * CC);
                pv4(v[0], p0.x, p1.x, acc0, acc1);
                pv4(v[1], p0.y, p1.y, acc0, acc1);
                pv4(v[2], p0.z, p1.z, acc0, acc1);
                pv4(v[3], p0.w, p1.w, acc0, acc1);
            }
        }
    }

    __syncthreads();
    float* ot = smem;             // [16][260]
    #pragma unroll
    for (int dc = 0; dc < 8; ++dc) {
        ot[(qg * 2 + 0) * 260 + cl * 8 + dc] = acc0[dc];
        ot[(qg * 2 + 1) * 260 + cl * 8 + dc] = acc1[dc];
    }
    __syncthreads();
    {
        const float g = ldf(gp, 0);
        const int eq = tid & 15, cg = tid >> 4;
        const float rl = 1.0f / l_s[eq];
        #pragma unroll
        for (int i = 0; i < 16; ++i) {
            const int c = cg * 16 + i;
            float v = ot[eq * 260 + c];
            float xv = ldf(xq, (size_t)c * NN + i0 + eq);
            stf(o, (size_t)c * NN + i0 + eq, fmaf(g, v * rl, xv));
        }
    }
}

extern "C" void kernel_launch(void* const* d_in, const int* in_sizes, int n_in,
                              void* d_out, int out_size, void* d_ws, size_t ws_size,
                              hipStream_t stream) {
    // workspace: 256B flag header + 10.0 MB buffers.
    // Layout: xf1(2M) xf2(2M) | union region (6M):
    //   bf16 sobel : xT(2M) Wr(2.25M)
    //   f32 sobel  : xT_hi(2M) xT_lo(2M)
    //   post-sobel : v1t(2M) v2t(2M) q1t k1t q2t k2t (0.5M each)
    if (ws_size < (size_t)(10 * 1024 * 1024 + 512 * 1024)) return;

    int* dflag = (int*)d_ws;
    char* base = (char*)d_ws + 256;
    bf16* xf1 = (bf16*)base;               // 2 MB
    bf16* xf2 = xf1 + 1048576;             // 2 MB
    char* ubase = (char*)(xf2 + 1048576);  // 6 MB union region
    bf16* xTb = (bf16*)ubase;                          // 2 MB   [4096][256]
    bf16* Wrb = (bf16*)(ubase + 2 * 1024 * 1024);      // 2.25 MB [9][512][256]
    bf16* xTh = (bf16*)ubase;                          // 2 MB (f32 path)
    bf16* xTl = (bf16*)(ubase + 2 * 1024 * 1024);      // 2 MB (f32 path)
    bf16* v1t = (bf16*)ubase;              // 2 MB (after sobel)
    bf16* v2t = v1t + 1048576;             // 2 MB
    float* q1t = (float*)(v2t + 1048576);  // 0.5 MB
    float* k1t = q1t + 131072;             // 0.5 MB
    float* q2t = k1t + 131072;             // 0.5 MB
    float* k2t = q2t + 131072;             // 0.5 MB

    detect_kernel<<<dim3(1), 256, 0, stream>>>((const unsigned short*)d_in[0], dflag);

    // ---- bf16 pipeline (want=0): plain bf16 MFMA sobel ----
    {
        typedef bf16 T;
        transpose_kernel<<<dim3(4, 64), 256, 0, stream>>>(dflag, (const T*)d_in[0], xTb);
        packw_kernel<<<dim3(1152), 256, 0, stream>>>(dflag, (const T*)d_in[2], (const T*)d_in[3], Wrb);
        sobel_mfma_kernel<<<dim3(8, 64), 256, 0, stream>>>(dflag, xTb, Wrb,
            (const T*)d_in[4], (const T*)d_in[5], xf1);
        transpose_kernel<<<dim3(4, 64), 256, 0, stream>>>(dflag, (const T*)d_in[1], xTb);
        packw_kernel<<<dim3(1152), 256, 0, stream>>>(dflag, (const T*)d_in[6], (const T*)d_in[7], Wrb);
        sobel_mfma_kernel<<<dim3(8, 64), 256, 0, stream>>>(dflag, xTb, Wrb,
            (const T*)d_in[8], (const T*)d_in[9], xf2);
        qkv_kernel<T><<<dim3(8, 8, 6), 256, 0, stream>>>(dflag, 0,
            (const T*)d_in[0], (const T*)d_in[1], xf1, xf2,
            (const T*)d_in[10], (const T*)d_in[11], (const T*)d_in[12], (const T*)d_in[13],
            (const T*)d_in[14], (const T*)d_in[15], (const T*)d_in[16], (const T*)d_in[17],
            (const T*)d_in[18], (const T*)d_in[19], (const T*)d_in[20], (const T*)d_in[21],
            q1t, k1t, v1t, q2t, k2t, v2t);
        attend_kernel<T><<<dim3(512), 256, 0, stream>>>(dflag, 0,
            q1t, k1t, v1t, (const T*)d_in[0], (const T*)d_in[22],
            q2t, k2t, v2t, (const T*)d_in[1], (const T*)d_in[23],
            (T*)d_out);
    }
    // ---- f32 pipeline (want=1): split-precision MFMA sobel ----
    {
        typedef float T;
        transpose_split_kernel<<<dim3(4, 64), 256, 0, stream>>>(dflag, (const T*)d_in[0], xTh, xTl);
        sobel_mfma_f32_kernel<<<dim3(8, 64), 256, 0, stream>>>(dflag, xTh, xTl,
            (const T*)d_in[2], (const T*)d_in[3], (const T*)d_in[4], (const T*)d_in[5], xf1);
        transpose_split_kernel<<<dim3(4, 64), 256, 0, stream>>>(dflag, (const T*)d_in[1], xTh, xTl);
        sobel_mfma_f32_kernel<<<dim3(8, 64), 256, 0, stream>>>(dflag, xTh, xTl,
            (const T*)d_in[6], (const T*)d_in[7], (const T*)d_in[8], (const T*)d_in[9], xf2);
        qkv_kernel<T><<<dim3(8, 8, 6), 256, 0, stream>>>(dflag, 1,
            (const T*)d_in[0], (const T*)d_in[1], xf1, xf2,
            (const T*)d_in[10], (const T*)d_in[11], (const T*)d_in[12], (const T*)d_in[13],
            (const T*)d_in[14], (const T*)d_in[15], (const T*)d_in[16], (const T*)d_in[17],
            (const T*)d_in[18], (const T*)d_in[19], (const T*)d_in[20], (const T*)d_in[21],
            q1t, k1t, v1t, q2t, k2t, v2t);
        attend_kernel<T><<<dim3(512), 256, 0, stream>>>(dflag, 1,
            q1t, k1t, v1t, (const T*)d_in[0], (const T*)d_in[22],
            q2t, k2t, v2t, (const T*)d_in[1], (const T*)d_in[23],
            (T*)d_out);
    }
}

// Round 4
// 582.545 us; speedup vs baseline: 2.6152x; 1.5132x over previous
//
#include <hip/hip_runtime.h>
#include <hip/hip_bf16.h>
#include <math.h>

#define CC 256
#define CQn 32
#define HH 64
#define WW 64
#define NN 4096
#define EPSF 1e-5f

typedef __hip_bfloat16 bf16;

typedef __attribute__((ext_vector_type(8))) short bf16x8v;
typedef __attribute__((ext_vector_type(4))) float f32x4v;

__device__ __forceinline__ float b2f(bf16 v) { return __bfloat162float(v); }
__device__ __forceinline__ bf16 f2b(float v) { return __float2bfloat16(v); }

template<typename T> __device__ __forceinline__ float ldf(const T* p, size_t i);
template<> __device__ __forceinline__ float ldf<float>(const float* p, size_t i) { return p[i]; }
template<> __device__ __forceinline__ float ldf<bf16>(const bf16* p, size_t i)  { return b2f(p[i]); }

__device__ __forceinline__ void stf(float* p, size_t i, float v) { p[i] = v; }
__device__ __forceinline__ void stf(bf16* p, size_t i, float v)  { p[i] = f2b(v); }

// ---------------- K0: dtype detector ----------------
// flag: 0 = data is bf16, 1 = data is f32.
__global__ __launch_bounds__(256)
void detect_kernel(const unsigned short* __restrict__ x1, int* __restrict__ flag)
{
    __shared__ int bad;
    if (threadIdx.x == 0) bad = 0;
    __syncthreads();
    int mybad = 0;
    for (int i = threadIdx.x; i < 16384; i += 256) {
        unsigned short u = x1[i];
        if ((u & 0x7F80u) == 0x7F80u) mybad = 1;
    }
    if (mybad) atomicOr(&bad, 1);
    __syncthreads();
    if (threadIdx.x == 0) *flag = bad ? 1 : 0;
}

// ---------------- bf16 path prep 1: x [256][4096] -> xT [4096][256] ----------------
__global__ __launch_bounds__(256)
void transpose_kernel(const int* __restrict__ dflag,
                      const bf16* __restrict__ x, bf16* __restrict__ xT)
{
    if (*dflag != 0) return;
    const int ci0 = blockIdx.x * 64;   // gridDim.x = 4
    const int p0  = blockIdx.y * 64;   // gridDim.y = 64
    const int t = threadIdx.x;
    const int r0 = t >> 3;             // 0..31
    const int ch = t & 7;              // 8 chunks of 8 bf16

    __shared__ bf16 tile[64][72];

    #pragma unroll
    for (int pass = 0; pass < 2; ++pass) {
        int r = pass * 32 + r0;
        uint4 v = *(const uint4*)(x + (size_t)(ci0 + r) * NN + p0 + ch * 8);
        *(uint4*)&tile[r][ch * 8] = v;
    }
    __syncthreads();
    #pragma unroll
    for (int pass = 0; pass < 2; ++pass) {
        int p = pass * 32 + r0;
        bf16 tmp[8];
        #pragma unroll
        for (int j = 0; j < 8; ++j) tmp[j] = tile[ch * 8 + j][p];
        *(uint4*)(xT + (size_t)(p0 + p) * CC + ci0 + ch * 8) = *(const uint4*)tmp;
    }
}

// ---------------- bf16 path prep 2: weights -> Wr[kk][m][ci], m = 2*o + isY ----------------
__global__ __launch_bounds__(256)
void packw_kernel(const int* __restrict__ dflag,
                  const bf16* __restrict__ wx, const bf16* __restrict__ wy,
                  bf16* __restrict__ Wr)
{
    if (*dflag != 0) return;
    const int lin = blockIdx.x * 256 + threadIdx.x;
    const int ci4 = lin & 63;
    const int m   = (lin >> 6) & 511;
    const int kk  = lin >> 15;                         // 0..8
    const int o   = m >> 1;
    const bf16* src = (m & 1) ? wy : wx;
    bf16 tmp[4];
    #pragma unroll
    for (int j = 0; j < 4; ++j)
        tmp[j] = src[(size_t)o * 2304 + (ci4 * 4 + j) * 9 + kk];
    *(uint2*)(Wr + ((size_t)kk * 512 + m) * CC + ci4 * 4) = *(const uint2*)tmp;
}

// ---------------- K1 (bf16): Sobel as implicit-GEMM MFMA ----------------
__global__ __launch_bounds__(256)
void sobel_mfma_kernel(const int* __restrict__ dflag,
                       const bf16* __restrict__ xT,
                       const bf16* __restrict__ Wr,
                       const bf16* __restrict__ bnx,
                       const bf16* __restrict__ bny,
                       bf16* __restrict__ xf)
{
    if (*dflag != 0) return;
    const int mt = blockIdx.x;      // 0..7
    const int y  = blockIdx.y;      // 0..63
    const int tid = threadIdx.x;
    const int w = tid >> 6, lane = tid & 63;
    const int wm = (w >> 1) * 32, wn = (w & 1) * 32;
    const int lr = lane & 15, q = lane >> 4;

    __shared__ char smem[18432];
    bf16* Asm = (bf16*)smem;                 // [64][40]
    bf16* Bsm = Asm + 64 * 40;               // [64][40]
    float* eb = (float*)smem;                // [64][72] epilogue reuse

    f32x4v acc[2][2];
    #pragma unroll
    for (int i = 0; i < 2; ++i)
        #pragma unroll
        for (int j = 0; j < 2; ++j) acc[i][j] = (f32x4v){0.f, 0.f, 0.f, 0.f};

    const int r = tid >> 2, ch = tid & 3;
    const bf16* Arow = Wr + (size_t)(mt * 64 + r) * CC + ch * 8;

    for (int kk = 0; kk < 9; ++kk) {
        const int dy = kk / 3 - 1, dx = kk - (kk / 3) * 3 - 1;
        const int ys = y + dy, xs = r + dx;
        const bool ok = (ys >= 0) && (ys < HH) && (xs >= 0) && (xs < WW);
        const bf16* Brow = xT + (size_t)(ys * WW + xs) * CC + ch * 8;
        const bf16* Ak = Arow + (size_t)kk * (512 * CC);
        for (int c0 = 0; c0 < CC; c0 += 32) {
            uint4 av = *(const uint4*)(Ak + c0);
            uint4 bv = make_uint4(0u, 0u, 0u, 0u);
            if (ok) bv = *(const uint4*)(Brow + c0);
            __syncthreads();
            *(uint4*)&Asm[r * 40 + ch * 8] = av;
            *(uint4*)&Bsm[r * 40 + ch * 8] = bv;
            __syncthreads();
            bf16x8v a0 = *(const bf16x8v*)&Asm[(wm + lr) * 40 + q * 8];
            bf16x8v a1 = *(const bf16x8v*)&Asm[(wm + 16 + lr) * 40 + q * 8];
            bf16x8v b0 = *(const bf16x8v*)&Bsm[(wn + lr) * 40 + q * 8];
            bf16x8v b1 = *(const bf16x8v*)&Bsm[(wn + 16 + lr) * 40 + q * 8];
            acc[0][0] = __builtin_amdgcn_mfma_f32_16x16x32_bf16(a0, b0, acc[0][0], 0, 0, 0);
            acc[0][1] = __builtin_amdgcn_mfma_f32_16x16x32_bf16(a0, b1, acc[0][1], 0, 0, 0);
            acc[1][0] = __builtin_amdgcn_mfma_f32_16x16x32_bf16(a1, b0, acc[1][0], 0, 0, 0);
            acc[1][1] = __builtin_amdgcn_mfma_f32_16x16x32_bf16(a1, b1, acc[1][1], 0, 0, 0);
        }
    }

    __syncthreads();
    #pragma unroll
    for (int fm = 0; fm < 2; ++fm)
        #pragma unroll
        for (int fn = 0; fn < 2; ++fn)
            #pragma unroll
            for (int reg = 0; reg < 4; ++reg)
                eb[(wm + fm * 16 + q * 4 + reg) * 72 + (wn + fn * 16 + lr)] = acc[fm][fn][reg];
    __syncthreads();
    {
        const int oc_l = tid >> 3, nch = tid & 7;
        const int oc = mt * 32 + oc_l;
        const float invx = b2f(bnx[oc]) * rsqrtf(b2f(bnx[3 * CC + oc]) + EPSF);
        const float bx   = b2f(bnx[CC + oc]);
        const float mx   = b2f(bnx[2 * CC + oc]);
        const float invy = b2f(bny[oc]) * rsqrtf(b2f(bny[3 * CC + oc]) + EPSF);
        const float by   = b2f(bny[CC + oc]);
        const float my   = b2f(bny[2 * CC + oc]);
        bf16 outv[8];
        #pragma unroll
        for (int j = 0; j < 8; ++j) {
            float gxv = eb[(2 * oc_l) * 72 + nch * 8 + j];
            float gyv = eb[(2 * oc_l + 1) * 72 + nch * 8 + j];
            float gxn = (gxv - mx) * invx + bx;
            float gyn = (gyv - my) * invy + by;
            outv[j] = f2b(sqrtf(gxn * gxn + gyn * gyn));
        }
        *(uint4*)(xf + (size_t)oc * NN + y * WW + nch * 8) = *(const uint4*)outv;
    }
}

// ---------------- f32 path prep: x f32 [256][4096] -> xT_hi + xT_lo bf16 [4096][256] ----------------
__global__ __launch_bounds__(256)
void transpose_split_kernel(const int* __restrict__ dflag,
                            const float* __restrict__ x,
                            bf16* __restrict__ xT_hi, bf16* __restrict__ xT_lo)
{
    if (*dflag != 1) return;
    const int ci0 = blockIdx.x * 64;   // 4
    const int p0  = blockIdx.y * 64;   // 64
    const int t = threadIdx.x;
    const int r = t >> 2, ch = t & 3;

    __shared__ float tile[64][76];

    {
        const float* src = x + (size_t)(ci0 + r) * NN + p0 + ch * 16;
        #pragma unroll
        for (int i = 0; i < 4; ++i) {
            float4 v = *(const float4*)(src + i * 4);
            *(float4*)&tile[r][ch * 16 + i * 4] = v;
        }
    }
    __syncthreads();
    {
        bf16 hi[16], lo[16];
        #pragma unroll
        for (int j = 0; j < 16; ++j) {
            float v = tile[ch * 16 + j][r];
            bf16 h = f2b(v);
            hi[j] = h;
            lo[j] = f2b(v - b2f(h));
        }
        size_t base = (size_t)(p0 + r) * CC + ci0 + ch * 16;
        *(uint4*)(xT_hi + base)     = ((const uint4*)hi)[0];
        *(uint4*)(xT_hi + base + 8) = ((const uint4*)hi)[1];
        *(uint4*)(xT_lo + base)     = ((const uint4*)lo)[0];
        *(uint4*)(xT_lo + base + 8) = ((const uint4*)lo)[1];
    }
}

// ---------------- K1 (f32): Sobel as split-precision implicit-GEMM MFMA ----------------
__global__ __launch_bounds__(256)
void sobel_mfma_f32_kernel(const int* __restrict__ dflag,
                           const bf16* __restrict__ xTh,
                           const bf16* __restrict__ xTl,
                           const float* __restrict__ wx,
                           const float* __restrict__ wy,
                           const float* __restrict__ bnx,
                           const float* __restrict__ bny,
                           bf16* __restrict__ xf)
{
    if (*dflag != 1) return;
    const int mt = blockIdx.x;      // 0..7
    const int y  = blockIdx.y;      // 0..63
    const int tid = threadIdx.x;
    const int w = tid >> 6, lane = tid & 63;
    const int wm = (w >> 1) * 32, wn = (w & 1) * 32;
    const int lr = lane & 15, q = lane >> 4;

    __shared__ char smem[20800];
    bf16* Ah = (bf16*)smem;          // [64][40]
    bf16* Al = Ah + 2560;            // [64][40]
    bf16* Bh = Al + 2560;            // [66][40] halo rows 0,65 zero
    bf16* Bl = Bh + 2640;            // [66][40]
    float* eb = (float*)smem;        // [64][72] epilogue reuse

    f32x4v acc[2][2];
    #pragma unroll
    for (int i = 0; i < 2; ++i)
        #pragma unroll
        for (int j = 0; j < 2; ++j) acc[i][j] = (f32x4v){0.f, 0.f, 0.f, 0.f};

    const int r = tid >> 2, ch = tid & 3;
    const int o = mt * 32 + (r >> 1);
    const float* wbase = ((r & 1) ? wy : wx) + (size_t)o * 2304;

    if (tid < 40) {
        Bh[tid] = f2b(0.f);           Bl[tid] = f2b(0.f);
        Bh[65 * 40 + tid] = f2b(0.f); Bl[65 * 40 + tid] = f2b(0.f);
    }

    for (int c0i = 0; c0i < 8; ++c0i) {
        const int c0 = c0i * 32;
        for (int dy = 0; dy < 3; ++dy) {
            const int ys = y + dy - 1;
            const float* wb = wbase + (size_t)(c0 + ch * 8) * 9 + dy * 3;
            float wv[8][3];
            #pragma unroll
            for (int j = 0; j < 8; ++j)
                #pragma unroll
                for (int d = 0; d < 3; ++d)
                    wv[j][d] = wb[j * 9 + d];
            uint4 bh = make_uint4(0u, 0u, 0u, 0u), bl = make_uint4(0u, 0u, 0u, 0u);
            if (ys >= 0 && ys < HH) {
                size_t bidx = (size_t)(ys * WW + r) * CC + c0 + ch * 8;
                bh = *(const uint4*)(xTh + bidx);
                bl = *(const uint4*)(xTl + bidx);
            }
            #pragma unroll
            for (int d = 0; d < 3; ++d) {
                __syncthreads();
                {
                    bf16 ah8[8], al8[8];
                    #pragma unroll
                    for (int j = 0; j < 8; ++j) {
                        float v = wv[j][d];
                        bf16 h = f2b(v);
                        ah8[j] = h;
                        al8[j] = f2b(v - b2f(h));
                    }
                    *(uint4*)&Ah[r * 40 + ch * 8] = *(const uint4*)ah8;
                    *(uint4*)&Al[r * 40 + ch * 8] = *(const uint4*)al8;
                    if (d == 0) {
                        *(uint4*)&Bh[(r + 1) * 40 + ch * 8] = bh;
                        *(uint4*)&Bl[(r + 1) * 40 + ch * 8] = bl;
                    }
                }
                __syncthreads();
                bf16x8v ah0 = *(const bf16x8v*)&Ah[(wm + lr) * 40 + q * 8];
                bf16x8v ah1 = *(const bf16x8v*)&Ah[(wm + 16 + lr) * 40 + q * 8];
                bf16x8v al0 = *(const bf16x8v*)&Al[(wm + lr) * 40 + q * 8];
                bf16x8v al1 = *(const bf16x8v*)&Al[(wm + 16 + lr) * 40 + q * 8];
                const int b0r = wn + lr + d, b1r = wn + 16 + lr + d;
                bf16x8v bh0 = *(const bf16x8v*)&Bh[b0r * 40 + q * 8];
                bf16x8v bh1 = *(const bf16x8v*)&Bh[b1r * 40 + q * 8];
                bf16x8v bl0 = *(const bf16x8v*)&Bl[b0r * 40 + q * 8];
                bf16x8v bl1 = *(const bf16x8v*)&Bl[b1r * 40 + q * 8];
                acc[0][0] = __builtin_amdgcn_mfma_f32_16x16x32_bf16(ah0, bh0, acc[0][0], 0, 0, 0);
                acc[0][0] = __builtin_amdgcn_mfma_f32_16x16x32_bf16(ah0, bl0, acc[0][0], 0, 0, 0);
                acc[0][0] = __builtin_amdgcn_mfma_f32_16x16x32_bf16(al0, bh0, acc[0][0], 0, 0, 0);
                acc[0][1] = __builtin_amdgcn_mfma_f32_16x16x32_bf16(ah0, bh1, acc[0][1], 0, 0, 0);
                acc[0][1] = __builtin_amdgcn_mfma_f32_16x16x32_bf16(ah0, bl1, acc[0][1], 0, 0, 0);
                acc[0][1] = __builtin_amdgcn_mfma_f32_16x16x32_bf16(al0, bh1, acc[0][1], 0, 0, 0);
                acc[1][0] = __builtin_amdgcn_mfma_f32_16x16x32_bf16(ah1, bh0, acc[1][0], 0, 0, 0);
                acc[1][0] = __builtin_amdgcn_mfma_f32_16x16x32_bf16(ah1, bl0, acc[1][0], 0, 0, 0);
                acc[1][0] = __builtin_amdgcn_mfma_f32_16x16x32_bf16(al1, bh0, acc[1][0], 0, 0, 0);
                acc[1][1] = __builtin_amdgcn_mfma_f32_16x16x32_bf16(ah1, bh1, acc[1][1], 0, 0, 0);
                acc[1][1] = __builtin_amdgcn_mfma_f32_16x16x32_bf16(ah1, bl1, acc[1][1], 0, 0, 0);
                acc[1][1] = __builtin_amdgcn_mfma_f32_16x16x32_bf16(al1, bh1, acc[1][1], 0, 0, 0);
            }
        }
    }

    __syncthreads();
    #pragma unroll
    for (int fm = 0; fm < 2; ++fm)
        #pragma unroll
        for (int fn = 0; fn < 2; ++fn)
            #pragma unroll
            for (int reg = 0; reg < 4; ++reg)
                eb[(wm + fm * 16 + q * 4 + reg) * 72 + (wn + fn * 16 + lr)] = acc[fm][fn][reg];
    __syncthreads();
    {
        const int oc_l = tid >> 3, nch = tid & 7;
        const int oc = mt * 32 + oc_l;
        const float invx = bnx[oc] * rsqrtf(bnx[3 * CC + oc] + EPSF);
        const float bx   = bnx[CC + oc];
        const float mx   = bnx[2 * CC + oc];
        const float invy = bny[oc] * rsqrtf(bny[3 * CC + oc] + EPSF);
        const float by   = bny[CC + oc];
        const float my   = bny[2 * CC + oc];
        bf16 outv[8];
        #pragma unroll
        for (int j = 0; j < 8; ++j) {
            float gxv = eb[(2 * oc_l) * 72 + nch * 8 + j];
            float gyv = eb[(2 * oc_l + 1) * 72 + nch * 8 + j];
            float gxn = (gxv - mx) * invx + bx;
            float gyn = (gyv - my) * invy + by;
            outv[j] = f2b(sqrtf(gxn * gxn + gyn * gyn));
        }
        *(uint4*)(xf + (size_t)oc * NN + y * WW + nch * 8) = *(const uint4*)outv;
    }
}

// ---------------- K2: 1x1 convs -> MFMA-ready q/k/v operands ----------------
// Qcat[n][64] = [Qh | Ql]; Kcat[n][96] = [Kh | Kh | Kl]  (bf16 hi/lo split of
// the f32 accumulator; QK^T = Qh*Kh + Ql*Kh + Qh*Kl, lo*lo dropped ~2^-18).
// V written transposed: vt[c][n] so PV B-fragments are contiguous.
template<typename T>
__global__ __launch_bounds__(256)
void qkv_kernel(const int* __restrict__ dflag, int want,
                const T* __restrict__ x1, const T* __restrict__ x2,
                const bf16* __restrict__ xf1, const bf16* __restrict__ xf2,
                const T* __restrict__ q1w, const T* __restrict__ q1b,
                const T* __restrict__ k1w, const T* __restrict__ k1b,
                const T* __restrict__ v1w, const T* __restrict__ v1b,
                const T* __restrict__ q2w, const T* __restrict__ q2b,
                const T* __restrict__ k2w, const T* __restrict__ k2b,
                const T* __restrict__ v2w, const T* __restrict__ v2b,
                bf16* __restrict__ qc1, bf16* __restrict__ kc1, bf16* __restrict__ v1t,
                bf16* __restrict__ qc2, bf16* __restrict__ kc2, bf16* __restrict__ v2t)
{
    if (*dflag != want) return;
    const int z = blockIdx.z;
    const T* Wb; const T* bias;
    const T* Xt = nullptr; const bf16* Xb = nullptr;
    bf16* outQ = nullptr; bf16* outK = nullptr; bf16* outV = nullptr; int O;
    switch (z) {
        case 0:  Wb = q1w; bias = q1b; Xt = x1;  outQ = qc1; O = CQn; break;
        case 1:  Wb = k1w; bias = k1b; Xb = xf2; outK = kc1; O = CQn; break;
        case 2:  Wb = v1w; bias = v1b; Xb = xf2; outV = v1t; O = CC;  break;
        case 3:  Wb = q2w; bias = q2b; Xt = x2;  outQ = qc2; O = CQn; break;
        case 4:  Wb = k2w; bias = k2b; Xb = xf1; outK = kc2; O = CQn; break;
        default: Wb = v2w; bias = v2b; Xb = xf1; outV = v2t; O = CC;  break;
    }
    const int o0 = blockIdx.x * 32;
    if (o0 >= O) return;
    const int n0 = blockIdx.y * 512;
    const int tid = threadIdx.x;

    __shared__ float lw[32 * 256];        // lw[o][c]
    for (int idx = tid; idx < 32 * 256; idx += 256)
        lw[idx] = ldf(Wb, (size_t)o0 * CC + idx);
    __syncthreads();

    const int n_a = n0 + tid;
    const int n_b = n0 + 256 + tid;

    float acca[32], accb[32];
    #pragma unroll
    for (int o = 0; o < 32; ++o) { acca[o] = 0.f; accb[o] = 0.f; }

    const float4* lw4 = (const float4*)lw;
    for (int c4 = 0; c4 < 64; ++c4) {
        float xa[4], xb[4];
        #pragma unroll
        for (int k = 0; k < 4; ++k) {
            size_t ia = (size_t)(c4 * 4 + k) * NN + n_a;
            size_t ib = (size_t)(c4 * 4 + k) * NN + n_b;
            if (Xt) { xa[k] = ldf(Xt, ia); xb[k] = ldf(Xt, ib); }
            else    { xa[k] = b2f(Xb[ia]); xb[k] = b2f(Xb[ib]); }
        }
        #pragma unroll
        for (int o = 0; o < 32; ++o) {
            float4 w4 = lw4[o * 64 + c4];
            acca[o] = fmaf(w4.x, xa[0], fmaf(w4.y, xa[1], fmaf(w4.z, xa[2], fmaf(w4.w, xa[3], acca[o]))));
            accb[o] = fmaf(w4.x, xb[0], fmaf(w4.y, xb[1], fmaf(w4.z, xb[2], fmaf(w4.w, xb[3], accb[o]))));
        }
    }
    #pragma unroll
    for (int o = 0; o < 32; ++o) {
        float bb = ldf(bias, o0 + o);
        acca[o] += bb; accb[o] += bb;
    }
    if (outV) {
        #pragma unroll
        for (int o = 0; o < 32; ++o) {
            outV[(size_t)(o0 + o) * NN + n_a] = f2b(acca[o]);
            outV[(size_t)(o0 + o) * NN + n_b] = f2b(accb[o]);
        }
    } else {
        #pragma unroll
        for (int half = 0; half < 2; ++half) {
            const float* ac = half ? accb : acca;
            const int n = half ? n_b : n_a;
            bf16 hi[32], lo[32];
            #pragma unroll
            for (int o = 0; o < 32; ++o) {
                float v = ac[o];
                bf16 h = f2b(v);
                hi[o] = h;
                lo[o] = f2b(v - b2f(h));
            }
            if (outQ) {
                bf16* row = outQ + (size_t)n * 64;
                #pragma unroll
                for (int u = 0; u < 4; ++u) {
                    ((uint4*)row)[u] = ((const uint4*)hi)[u];
                    ((uint4*)(row + 32))[u] = ((const uint4*)lo)[u];
                }
            } else {
                bf16* row = outK + (size_t)n * 96;
                #pragma unroll
                for (int u = 0; u < 4; ++u) {
                    ((uint4*)row)[u] = ((const uint4*)hi)[u];
                    ((uint4*)(row + 32))[u] = ((const uint4*)hi)[u];
                    ((uint4*)(row + 64))[u] = ((const uint4*)lo)[u];
                }
            }
        }
    }
}

// ---------------- K3: MFMA flash attention ----------------
// 512 blocks (att = b>>8, 16-query tile), 256 thr / 4 waves, 2 blocks/CU.
// Per 64-key tile: stage Kcat[64][104] + Vt[256][72] -> each wave: QK^T
// (12 mfma, K=96 split), in-register online softmax (row=reg, shfl_xor over
// 16-lane groups), P split to shared bf16 hi/lo [16][72] (wave w writes key
// quarter nf==w), then PV (16 mfma: 4 c-frags x 2 ksteps x {Ph,Pl}).
template<typename T>
__global__ __launch_bounds__(256)
void attend_mfma_kernel(const int* __restrict__ dflag, int want,
                        const bf16* __restrict__ qc1, const bf16* __restrict__ kc1,
                        const bf16* __restrict__ v1, const T* __restrict__ x1,
                        const T* __restrict__ g1,
                        const bf16* __restrict__ qc2, const bf16* __restrict__ kc2,
                        const bf16* __restrict__ v2, const T* __restrict__ x2,
                        const T* __restrict__ g2,
                        T* __restrict__ out)
{
    if (*dflag != want) return;
    const int att = blockIdx.x >> 8;
    const int i0 = (blockIdx.x & 255) * 16;
    const bf16* qc = att ? qc2 : qc1;
    const bf16* kc = att ? kc2 : kc1;
    const bf16* vt = att ? v2 : v1;
    const T* xq = att ? x2 : x1;
    const T* gp = att ? g2 : g1;
    T* o = out + (size_t)att * CC * NN;

    const int tid = threadIdx.x;
    const int w = tid >> 6, lane = tid & 63;
    const int lr = lane & 15, g = lane >> 4;

    __shared__ __align__(16) bf16 lds[27392];   // 54784 B
    bf16* Kc = lds;                  // [64][104]   (6656)
    bf16* Vt = lds + 6656;           // [256][72]   (18432)
    bf16* Ph = lds + 25088;          // [16][72]    (1152)
    bf16* Pl = lds + 26240;          // [16][72]    (1152)

    // Q fragments: row q = i0+lr, k-chunk g*8 (A-frag layout)
    const bf16* qrow = qc + (size_t)(i0 + lr) * 64 + g * 8;
    bf16x8v qh = *(const bf16x8v*)(qrow);
    bf16x8v ql = *(const bf16x8v*)(qrow + 32);

    float m_r[4], l_r[4];
    #pragma unroll
    for (int r = 0; r < 4; ++r) { m_r[r] = -INFINITY; l_r[r] = 0.f; }
    f32x4v oacc[4];
    #pragma unroll
    for (int f = 0; f < 4; ++f) oacc[f] = (f32x4v){0.f, 0.f, 0.f, 0.f};

    for (int jt = 0; jt < 64; ++jt) {
        const int j0 = jt * 64;
        __syncthreads();                      // prior tile LDS reads done
        // stage Kcat: 768 uint4
        #pragma unroll
        for (int s = 0; s < 3; ++s) {
            int idx = tid + s * 256;
            int row = idx / 12, cq = idx - row * 12;
            uint4 u = *(const uint4*)(kc + (size_t)(j0 + row) * 96 + cq * 8);
            *(uint4*)&Kc[row * 104 + cq * 8] = u;
        }
        // stage Vt: row c = tid (128 B contiguous from global)
        {
            const bf16* src = vt + (size_t)tid * NN + j0;
            bf16* dst = Vt + tid * 72;
            #pragma unroll
            for (int s = 0; s < 8; ++s)
                *(uint4*)(dst + s * 8) = *(const uint4*)(src + s * 8);
        }
        __syncthreads();

        // ---- QK^T: e[nf][r] = energy(q = g*4+r, key = nf*16+lr) ----
        f32x4v e[4];
        #pragma unroll
        for (int nf = 0; nf < 4; ++nf) {
            const bf16* kr = Kc + (nf * 16 + lr) * 104 + g * 8;
            bf16x8v b0 = *(const bf16x8v*)(kr);
            bf16x8v b1 = *(const bf16x8v*)(kr + 32);
            bf16x8v b2 = *(const bf16x8v*)(kr + 64);
            f32x4v z = (f32x4v){0.f, 0.f, 0.f, 0.f};
            z = __builtin_amdgcn_mfma_f32_16x16x32_bf16(qh, b0, z, 0, 0, 0);
            z = __builtin_amdgcn_mfma_f32_16x16x32_bf16(ql, b1, z, 0, 0, 0);
            z = __builtin_amdgcn_mfma_f32_16x16x32_bf16(qh, b2, z, 0, 0, 0);
            e[nf] = z;
        }
        // ---- online softmax (rows q = g*4+r; reduce over nf + 16 lanes) ----
        float alpha[4];
        #pragma unroll
        for (int r = 0; r < 4; ++r) {
            float tm = fmaxf(fmaxf(e[0][r], e[1][r]), fmaxf(e[2][r], e[3][r]));
            #pragma unroll
            for (int msk = 1; msk <= 8; msk <<= 1)
                tm = fmaxf(tm, __shfl_xor(tm, msk));
            float mn = fmaxf(m_r[r], tm);
            alpha[r] = __expf(m_r[r] - mn);
            m_r[r] = mn;
            float s = 0.f;
            #pragma unroll
            for (int nf = 0; nf < 4; ++nf) {
                float p = __expf(e[nf][r] - mn);
                s += p;
                if (nf == w) {                 // this wave owns key quarter w
                    bf16 ph = f2b(p);
                    Ph[(g * 4 + r) * 72 + nf * 16 + lr] = ph;
                    Pl[(g * 4 + r) * 72 + nf * 16 + lr] = f2b(p - b2f(ph));
                }
            }
            #pragma unroll
            for (int msk = 1; msk <= 8; msk <<= 1)
                s += __shfl_xor(s, msk);
            l_r[r] = l_r[r] * alpha[r] + s;
        }
        __syncthreads();                      // P complete (cross-wave)

        // ---- PV ----
        #pragma unroll
        for (int f = 0; f < 4; ++f)
            #pragma unroll
            for (int r = 0; r < 4; ++r)
                oacc[f][r] *= alpha[r];
        bf16x8v pah[2], pal[2];
        #pragma unroll
        for (int ks = 0; ks < 2; ++ks) {
            pah[ks] = *(const bf16x8v*)&Ph[lr * 72 + ks * 32 + g * 8];
            pal[ks] = *(const bf16x8v*)&Pl[lr * 72 + ks * 32 + g * 8];
        }
        #pragma unroll
        for (int f = 0; f < 4; ++f) {
            const bf16* vr = Vt + (w * 64 + f * 16 + lr) * 72 + g * 8;
            #pragma unroll
            for (int ks = 0; ks < 2; ++ks) {
                bf16x8v bv = *(const bf16x8v*)(vr + ks * 32);
                oacc[f] = __builtin_amdgcn_mfma_f32_16x16x32_bf16(pah[ks], bv, oacc[f], 0, 0, 0);
                oacc[f] = __builtin_amdgcn_mfma_f32_16x16x32_bf16(pal[ks], bv, oacc[f], 0, 0, 0);
            }
        }
    }

    // ---- epilogue: transpose via LDS, divide by l, residual, store ----
    __syncthreads();
    float* ob = (float*)lds;          // [256][20]
    float* ls = ob + 5120;            // [16]
    #pragma unroll
    for (int f = 0; f < 4; ++f)
        #pragma unroll
        for (int r = 0; r < 4; ++r)
            ob[(w * 64 + f * 16 + lr) * 20 + g * 4 + r] = oacc[f][r];
    if (w == 0 && lr == 0) {
        #pragma unroll
        for (int r = 0; r < 4; ++r) ls[g * 4 + r] = l_r[r];
    }
    __syncthreads();
    {
        const float gm = ldf(gp, 0);
        const int c = tid;
        const size_t rowo = (size_t)c * NN + i0;
        #pragma unroll
        for (int q = 0; q < 16; ++q) {
            float v = ob[c * 20 + q] / ls[q];
            float xv = ldf(xq, rowo + q);
            stf(o, rowo + q, fmaf(gm, v, xv));
        }
    }
}

extern "C" void kernel_launch(void* const* d_in, const int* in_sizes, int n_in,
                              void* d_out, int out_size, void* d_ws, size_t ws_size,
                              hipStream_t stream) {
    // workspace: 256B flag + xf1(2M) xf2(2M) + union(6.5M):
    //   sobel phase : xT/xTh(2M) Wr|xTl(2.25M/2M)
    //   post-sobel  : v1t(2M) v2t(2M) qc1(512K) kc1(768K) qc2(512K) kc2(768K)
    // total 11,010,304 B (prior session proved ws_size >= 11 MB).
    if (ws_size < (size_t)11010304) return;

    int* dflag = (int*)d_ws;
    char* base = (char*)d_ws + 256;
    bf16* xf1 = (bf16*)base;               // 2 MB
    bf16* xf2 = xf1 + 1048576;             // 2 MB
    char* ubase = (char*)(xf2 + 1048576);  // 6.5 MB union region
    bf16* xTb = (bf16*)ubase;                          // bf16 sobel
    bf16* Wrb = (bf16*)(ubase + 2 * 1024 * 1024);
    bf16* xTh = (bf16*)ubase;                          // f32 sobel
    bf16* xTl = (bf16*)(ubase + 2 * 1024 * 1024);
    bf16* v1t = (bf16*)ubase;              // [256][4096] bf16, 2 MB
    bf16* v2t = v1t + 1048576;             // 2 MB
    bf16* qc1 = v2t + 1048576;             // [4096][64], 512 KB
    bf16* kc1 = qc1 + 262144;              // [4096][96], 768 KB
    bf16* qc2 = kc1 + 393216;              // 512 KB
    bf16* kc2 = qc2 + 262144;              // 768 KB

    detect_kernel<<<dim3(1), 256, 0, stream>>>((const unsigned short*)d_in[0], dflag);

    // ---- bf16 pipeline (want=0) ----
    {
        typedef bf16 T;
        transpose_kernel<<<dim3(4, 64), 256, 0, stream>>>(dflag, (const T*)d_in[0], xTb);
        packw_kernel<<<dim3(1152), 256, 0, stream>>>(dflag, (const T*)d_in[2], (const T*)d_in[3], Wrb);
        sobel_mfma_kernel<<<dim3(8, 64), 256, 0, stream>>>(dflag, xTb, Wrb,
            (const T*)d_in[4], (const T*)d_in[5], xf1);
        transpose_kernel<<<dim3(4, 64), 256, 0, stream>>>(dflag, (const T*)d_in[1], xTb);
        packw_kernel<<<dim3(1152), 256, 0, stream>>>(dflag, (const T*)d_in[6], (const T*)d_in[7], Wrb);
        sobel_mfma_kernel<<<dim3(8, 64), 256, 0, stream>>>(dflag, xTb, Wrb,
            (const T*)d_in[8], (const T*)d_in[9], xf2);
        qkv_kernel<T><<<dim3(8, 8, 6), 256, 0, stream>>>(dflag, 0,
            (const T*)d_in[0], (const T*)d_in[1], xf1, xf2,
            (const T*)d_in[10], (const T*)d_in[11], (const T*)d_in[12], (const T*)d_in[13],
            (const T*)d_in[14], (const T*)d_in[15], (const T*)d_in[16], (const T*)d_in[17],
            (const T*)d_in[18], (const T*)d_in[19], (const T*)d_in[20], (const T*)d_in[21],
            qc1, kc1, v1t, qc2, kc2, v2t);
        attend_mfma_kernel<T><<<dim3(512), 256, 0, stream>>>(dflag, 0,
            qc1, kc1, v1t, (const T*)d_in[0], (const T*)d_in[22],
            qc2, kc2, v2t, (const T*)d_in[1], (const T*)d_in[23],
            (T*)d_out);
    }
    // ---- f32 pipeline (want=1) ----
    {
        typedef float T;
        transpose_split_kernel<<<dim3(4, 64), 256, 0, stream>>>(dflag, (const T*)d_in[0], xTh, xTl);
        sobel_mfma_f32_kernel<<<dim3(8, 64), 256, 0, stream>>>(dflag, xTh, xTl,
            (const T*)d_in[2], (const T*)d_in[3], (const T*)d_in[4], (const T*)d_in[5], xf1);
        transpose_split_kernel<<<dim3(4, 64), 256, 0, stream>>>(dflag, (const T*)d_in[1], xTh, xTl);
        sobel_mfma_f32_kernel<<<dim3(8, 64), 256, 0, stream>>>(dflag, xTh, xTl,
            (const T*)d_in[6], (const T*)d_in[7], (const T*)d_in[8], (const T*)d_in[9], xf2);
        qkv_kernel<T><<<dim3(8, 8, 6), 256, 0, stream>>>(dflag, 1,
            (const T*)d_in[0], (const T*)d_in[1], xf1, xf2,
            (const T*)d_in[10], (const T*)d_in[11], (const T*)d_in[12], (const T*)d_in[13],
            (const T*)d_in[14], (const T*)d_in[15], (const T*)d_in[16], (const T*)d_in[17],
            (const T*)d_in[18], (const T*)d_in[19], (const T*)d_in[20], (const T*)d_in[21],
            qc1, kc1, v1t, qc2, kc2, v2t);
        attend_mfma_kernel<T><<<dim3(512), 256, 0, stream>>>(dflag, 1,
            qc1, kc1, v1t, (const T*)d_in[0], (const T*)d_in[22],
            qc2, kc2, v2t, (const T*)d_in[1], (const T*)d_in[23],
            (T*)d_out);
    }
}